// Round 1
// baseline (2806.125 us; speedup 1.0000x reference)
//
#include <hip/hip_runtime.h>
#include <hip/hip_bf16.h>
#include <math.h>

// EvolveGCN-H on MI355X. B=2, T=8, N=10000, F=DIN=DOUT=128, E=320000, 2 layers.
// Structure per (t,c): scores -> top-128 (bitonic, composite key) -> gather ->
// GRU (gemm + gates) -> dense GEMM -> CSR propagation (+bias, relu).
// CSR by destination built once per launch. Layer-1 GEMM/prop only at t=T-1.

#define BB 2
#define TT 8
#define FF 128
#define GG 384   // 3*FF

// ---------------- edge fetch (int64 vs int32 runtime detect) ----------------
__global__ void detect_kernel(const int* ei32, int E, int* flag) {
  int e = blockIdx.x * 256 + threadIdx.x;
  if (e < E && ei32[2 * e + 1] != 0) atomicOr(flag, 1);
}

__device__ __forceinline__ void edge_fetch(const void* ei, int is32, int E,
                                           int e, const float* ew,
                                           int& row, int& col, float& w) {
  if (e < E) {
    if (is32) {
      const int* p = (const int*)ei;
      row = p[e]; col = p[E + e];
    } else {
      const long long* p = (const long long*)ei;
      row = (int)p[e]; col = (int)p[(long long)E + e];
    }
    w = ew[e];
  } else {           // self loop
    row = col = e - E; w = 1.0f;
  }
}

__global__ void hist_kernel(const void* ei, const int* flag, int E, int N,
                            const float* __restrict__ ew,
                            float* __restrict__ deg, int* __restrict__ counts) {
  int e = blockIdx.x * 256 + threadIdx.x;
  if (e >= E + N) return;
  int row, col; float w;
  edge_fetch(ei, *flag, E, e, ew, row, col, w);
  atomicAdd(&deg[col], w);
  atomicAdd(&counts[col], 1);
}

__global__ void dinv_kernel(const float* __restrict__ deg,
                            float* __restrict__ dinv, int N) {
  int n = blockIdx.x * 256 + threadIdx.x;
  if (n < N) { float d = deg[n]; dinv[n] = (d > 0.f) ? 1.0f / sqrtf(d) : 0.f; }
}

__global__ __launch_bounds__(1024) void scan_kernel(const int* __restrict__ counts,
                                                    int* __restrict__ offsets,
                                                    int N, int EN) {
  __shared__ int part[1024];
  int tid = threadIdx.x;
  int base = tid * 10;
  int lc[10]; int s = 0;
  for (int q = 0; q < 10; ++q) {
    int idx = base + q;
    int cv = (idx < N) ? counts[idx] : 0;
    lc[q] = cv; s += cv;
  }
  part[tid] = s;
  __syncthreads();
  for (int off = 1; off < 1024; off <<= 1) {
    int v = (tid >= off) ? part[tid - off] : 0;
    __syncthreads();
    part[tid] += v;
    __syncthreads();
  }
  int run = part[tid] - s;  // exclusive prefix
  for (int q = 0; q < 10; ++q) {
    int idx = base + q;
    if (idx < N) { offsets[idx] = run; run += lc[q]; }
  }
  if (tid == 0) offsets[N] = EN;
}

__global__ void scatter_kernel(const void* ei, const int* flag, int E, int N,
                               const float* __restrict__ ew,
                               const float* __restrict__ dinv,
                               const int* __restrict__ offs,
                               int* __restrict__ cursors,
                               int* __restrict__ srt, float* __restrict__ wst) {
  int e = blockIdx.x * 256 + threadIdx.x;
  if (e >= E + N) return;
  int row, col; float w;
  edge_fetch(ei, *flag, E, e, ew, row, col, w);
  int pos = atomicAdd(&cursors[col], 1);
  int slot = offs[col] + pos;
  srt[slot] = row;
  wst[slot] = dinv[row] * w * dinv[col];
}

// ---------------- misc setup ----------------
__global__ void winit_kernel(const float* __restrict__ W0, float* __restrict__ Wbuf) {
  int i = blockIdx.x * 256 + threadIdx.x;     // 2*2*16384 total
  if (i >= 2 * BB * FF * FF) return;
  int c = i >> 15;            // / (BB*FF*FF)
  int rem = i & 32767;
  int e = rem & 16383;
  Wbuf[(size_t)c * 2 * BB * FF * FF + rem] = W0[c * FF * FF + e];
}

__global__ void pnorm_kernel(const float* __restrict__ p, float* __restrict__ pinv) {
  int c = blockIdx.x, tid = threadIdx.x;  // 128 threads
  float v = p[c * FF + tid];
  float s = v * v;
  for (int o = 32; o; o >>= 1) s += __shfl_xor(s, o, 64);
  __shared__ float red[2];
  if ((tid & 63) == 0) red[tid >> 6] = s;
  __syncthreads();
  if (tid == 0) pinv[c] = 1.0f / sqrtf(red[0] + red[1]);
}

// ---------------- scores + top-k ----------------
__global__ __launch_bounds__(256) void scores_kernel(const float* __restrict__ act,
                                                     size_t bstride,
                                                     const float* __restrict__ p,
                                                     const float* __restrict__ pinv,
                                                     unsigned long long* __restrict__ keys,
                                                     int N, int KPAD) {
  int b = blockIdx.y;
  int wid = threadIdx.x >> 6, lane = threadIdx.x & 63;
  int n = blockIdx.x * 4 + wid;
  if (n >= N) return;
  const float2* row = (const float2*)(act + (size_t)b * bstride + (size_t)n * FF);
  const float2* p2 = (const float2*)p;
  float2 a = row[lane], pp = p2[lane];
  float s = a.x * pp.x + a.y * pp.y;
  for (int o = 32; o; o >>= 1) s += __shfl_xor(s, o, 64);
  if (lane == 0) {
    s *= *pinv;
    unsigned u = __float_as_uint(s);
    u = (u & 0x80000000u) ? ~u : (u | 0x80000000u);
    keys[(size_t)b * KPAD + n] = ((unsigned long long)u << 32) | (unsigned)(~n);
  }
}

template <int NSZ, int NT>
__device__ __forceinline__ void bitonic_desc(unsigned long long* sk) {
  for (int k = 2; k <= NSZ; k <<= 1)
    for (int j = k >> 1; j > 0; j >>= 1) {
      __syncthreads();
      for (int i = threadIdx.x; i < NSZ; i += NT) {
        int ixj = i ^ j;
        if (ixj > i) {
          unsigned long long a = sk[i], c = sk[ixj];
          bool asc = (i & k) != 0;
          bool sw = asc ? (a > c) : (a < c);
          if (sw) { sk[i] = c; sk[ixj] = a; }
        }
      }
    }
  __syncthreads();
}

__global__ __launch_bounds__(256) void topk1_kernel(const unsigned long long* __restrict__ keys,
                                                    unsigned long long* __restrict__ cand,
                                                    int KPAD, int NCAND) {
  int chunk = blockIdx.x, b = blockIdx.y, tid = threadIdx.x;
  __shared__ unsigned long long sk[1024];
  for (int r = 0; r < 4; ++r) {
    int i = tid + r * 256;
    sk[i] = keys[(size_t)b * KPAD + chunk * 1024 + i];
  }
  bitonic_desc<1024, 256>(sk);
  if (tid < 128) cand[(size_t)b * NCAND + chunk * 128 + tid] = sk[tid];
}

__global__ __launch_bounds__(256) void topk2_kernel(const unsigned long long* __restrict__ cand,
                                                    int NCAND,
                                                    int* __restrict__ idx_sel,
                                                    float* __restrict__ gate_sel) {
  int b = blockIdx.x, tid = threadIdx.x;
  __shared__ unsigned long long sk[2048];
  for (int r = 0; r < 8; ++r) {
    int i = tid + r * 256;
    sk[i] = (i < NCAND) ? cand[(size_t)b * NCAND + i] : 0ULL;
  }
  bitonic_desc<2048, 256>(sk);
  if (tid < 128) {
    unsigned long long kk = sk[tid];
    unsigned n = ~((unsigned)kk);
    unsigned u = (unsigned)(kk >> 32);
    float sc = (u & 0x80000000u) ? __uint_as_float(u & 0x7FFFFFFFu)
                                 : __uint_as_float(~u);
    idx_sel[b * 128 + tid] = (int)n;
    gate_sel[b * 128 + tid] = tanhf(sc);
  }
}

// ---------------- GRU ----------------
__global__ __launch_bounds__(128) void gather_kernel(const float* __restrict__ act,
                                                     size_t bstride,
                                                     const float* __restrict__ Wcur,
                                                     const int* __restrict__ idx_sel,
                                                     const float* __restrict__ gate_sel,
                                                     float* __restrict__ pooled,
                                                     float* __restrict__ hgbuf) {
  int j = blockIdx.x, b = blockIdx.y, tid = threadIdx.x;
  int n = idx_sel[b * 128 + j];
  float g = gate_sel[b * 128 + j];
  pooled[((size_t)b * 128 + j) * FF + tid] =
      act[(size_t)b * bstride + (size_t)n * FF + tid] * g;
  hgbuf[((size_t)b * 128 + j) * FF + tid] =
      Wcur[((size_t)b * FF + tid) * FF + j];   // hg[j,k] = W[b,k,j]
}

__global__ __launch_bounds__(256) void grugemm_kernel(const float* __restrict__ pooled,
                                                      const float* __restrict__ hgbuf,
                                                      const float* __restrict__ wih,
                                                      const float* __restrict__ whh,
                                                      const float* __restrict__ bih,
                                                      const float* __restrict__ bhh,
                                                      float* __restrict__ gi,
                                                      float* __restrict__ gh) {
  int b = blockIdx.x, jt = blockIdx.y, gt = blockIdx.z;
  int jbase = jt * 32, gbase = gt * 32;
  __shared__ float sp[32][129], sh[32][129], sw[32][129];
  int tid = threadIdx.x;
  for (int e = tid; e < 32 * 128; e += 256) {
    int r = e >> 7, k = e & 127;
    sp[r][k] = pooled[((size_t)b * 128 + jbase + r) * FF + k];
    sh[r][k] = hgbuf[((size_t)b * 128 + jbase + r) * FF + k];
    sw[r][k] = wih[(gbase + r) * FF + k];
  }
  __syncthreads();
  int gl = tid & 31, jg = tid >> 5;  // jg in 0..7
  float acc[4] = {0.f, 0.f, 0.f, 0.f};
  for (int k = 0; k < 128; ++k) {
    float wv = sw[gl][k];
    acc[0] += sp[jg][k] * wv;
    acc[1] += sp[jg + 8][k] * wv;
    acc[2] += sp[jg + 16][k] * wv;
    acc[3] += sp[jg + 24][k] * wv;
  }
  float bi = bih[gbase + gl];
#pragma unroll
  for (int q = 0; q < 4; ++q)
    gi[((size_t)b * 128 + jbase + jg + q * 8) * GG + gbase + gl] = acc[q] + bi;
  __syncthreads();
  for (int e = tid; e < 32 * 128; e += 256) {
    int r = e >> 7, k = e & 127;
    sw[r][k] = whh[(gbase + r) * FF + k];
  }
  __syncthreads();
  float ac2[4] = {0.f, 0.f, 0.f, 0.f};
  for (int k = 0; k < 128; ++k) {
    float wv = sw[gl][k];
    ac2[0] += sh[jg][k] * wv;
    ac2[1] += sh[jg + 8][k] * wv;
    ac2[2] += sh[jg + 16][k] * wv;
    ac2[3] += sh[jg + 24][k] * wv;
  }
  float bh = bhh[gbase + gl];
#pragma unroll
  for (int q = 0; q < 4; ++q)
    gh[((size_t)b * 128 + jbase + jg + q * 8) * GG + gbase + gl] = ac2[q] + bh;
}

__global__ __launch_bounds__(256) void grucomb_kernel(const float* __restrict__ gi,
                                                      const float* __restrict__ gh,
                                                      const float* __restrict__ hgbuf,
                                                      float* __restrict__ Wnew) {
  int idx = blockIdx.x * 256 + threadIdx.x;   // BB*128*128
  if (idx >= BB * FF * FF) return;
  int b = idx >> 14;
  int r = idx & 16383;
  int k = r >> 7, j = r & 127;                // consecutive tid -> consecutive j
  size_t base = ((size_t)b * 128 + j) * GG;
  float gir = gi[base + k], giz = gi[base + 128 + k], gin = gi[base + 256 + k];
  float ghr = gh[base + k], ghz = gh[base + 128 + k], ghn = gh[base + 256 + k];
  float rr = 1.0f / (1.0f + expf(-(gir + ghr)));
  float zz = 1.0f / (1.0f + expf(-(giz + ghz)));
  float nn = tanhf(gin + rr * ghn);
  float h = hgbuf[((size_t)b * 128 + j) * FF + k];
  float hnew = (1.0f - zz) * nn + zz * h;
  Wnew[((size_t)b * FF + k) * FF + j] = hnew;  // W[b,k,j] = newh[j,k]
}

// ---------------- dense GEMM: o[b,n,:] = act[b,n,:] @ W[b,:,:] ----------------
__global__ __launch_bounds__(256) void gemm_kernel(const float* __restrict__ act,
                                                   size_t bstride,
                                                   const float* __restrict__ W,
                                                   float* __restrict__ obuf, int N) {
  int nb = blockIdx.x, b = blockIdx.y;
  __shared__ float As[64][33];
  __shared__ float Bs[32][128];
  int tid = threadIdx.x;
  int tn = tid & 15, td = tid >> 4;
  float acc[4][8] = {};
  const float* Ab = act + (size_t)b * bstride;
  const float* Wb = W + (size_t)b * FF * FF;
  for (int kc = 0; kc < 4; ++kc) {
    int k0 = kc * 32;
    __syncthreads();
    for (int e = tid; e < 64 * 32; e += 256) {
      int r = e >> 5, kk = e & 31;
      int n = nb * 64 + r;
      As[r][kk] = (n < N) ? Ab[(size_t)n * FF + k0 + kk] : 0.f;
    }
    for (int e = tid; e < 32 * 128; e += 256) {
      int r = e >> 7, dd = e & 127;
      Bs[r][dd] = Wb[(k0 + r) * FF + dd];
    }
    __syncthreads();
    for (int kk = 0; kk < 32; ++kk) {
      float bv[8];
#pragma unroll
      for (int j = 0; j < 8; ++j) bv[j] = Bs[kk][td * 8 + j];
#pragma unroll
      for (int i = 0; i < 4; ++i) {
        float av = As[tn * 4 + i][kk];
#pragma unroll
        for (int j = 0; j < 8; ++j) acc[i][j] += av * bv[j];
      }
    }
  }
#pragma unroll
  for (int i = 0; i < 4; ++i) {
    int n = nb * 64 + tn * 4 + i;
    if (n < N) {
      float4* dst = (float4*)(obuf + ((size_t)b * N + n) * FF + td * 8);
      dst[0] = make_float4(acc[i][0], acc[i][1], acc[i][2], acc[i][3]);
      dst[1] = make_float4(acc[i][4], acc[i][5], acc[i][6], acc[i][7]);
    }
  }
}

// ---------------- CSR propagation + bias + relu ----------------
__global__ __launch_bounds__(128) void prop_kernel(const float* __restrict__ o,
                                                   const int* __restrict__ srt,
                                                   const float* __restrict__ wst,
                                                   const int* __restrict__ offs,
                                                   const float* __restrict__ bias,
                                                   float* __restrict__ outp, int N) {
  int v = blockIdx.x, b = blockIdx.y, tid = threadIdx.x;
  int e0 = offs[v], e1 = offs[v + 1];
  __shared__ int ls[128];
  __shared__ float lw[128];
  float acc = 0.f;
  const float* ob = o + (size_t)b * N * FF;
  for (int base = e0; base < e1; base += 128) {
    int cnt = min(128, e1 - base);
    __syncthreads();
    if (tid < cnt) { ls[tid] = srt[base + tid]; lw[tid] = wst[base + tid]; }
    __syncthreads();
    for (int i = 0; i < cnt; ++i)
      acc += lw[i] * ob[(size_t)ls[i] * FF + tid];
  }
  outp[((size_t)b * N + v) * FF + tid] = fmaxf(acc + bias[tid], 0.f);
}

// ---------------- host ----------------
extern "C" void kernel_launch(void* const* d_in, const int* in_sizes, int n_in,
                              void* d_out, int out_size, void* d_ws, size_t ws_size,
                              hipStream_t stream) {
  const float* x   = (const float*)d_in[0];
  const void*  ei  = d_in[1];
  const float* ew  = (const float*)d_in[2];
  const float* W0  = (const float*)d_in[3];
  const float* p   = (const float*)d_in[4];
  const float* wih = (const float*)d_in[5];
  const float* whh = (const float*)d_in[6];
  const float* bih = (const float*)d_in[7];
  const float* bhh = (const float*)d_in[8];
  const float* bias= (const float*)d_in[9];

  const int E  = in_sizes[2];
  const int N  = in_sizes[0] / (BB * TT * FF);
  const int EN = E + N;
  const int CH = (N + 1023) / 1024;      // top-k stage-1 chunks (10)
  const int KPAD = CH * 1024;            // 10240
  const int NCAND = CH * 128;            // 1280

  // ---- workspace carve (deterministic every call) ----
  char* w = (char*)d_ws;
  auto alloc = [&](size_t bytes) -> char* {
    char* r = w; w += (bytes + 255) & ~(size_t)255; return r;
  };
  float* deg      = (float*)alloc((size_t)N * 4);
  float* dinv     = (float*)alloc((size_t)N * 4);
  int*   counts   = (int*)  alloc((size_t)N * 4);
  int*   offsets  = (int*)  alloc((size_t)(N + 1) * 4);
  int*   cursors  = (int*)  alloc((size_t)N * 4);
  int*   flag     = (int*)  alloc(4);
  float* pinv     = (float*)alloc(2 * 4);
  int*   srt      = (int*)  alloc((size_t)EN * 4);
  float* wst      = (float*)alloc((size_t)EN * 4);
  unsigned long long* keys = (unsigned long long*)alloc((size_t)BB * KPAD * 8);
  unsigned long long* cand = (unsigned long long*)alloc((size_t)BB * NCAND * 8);
  int*   idx_sel  = (int*)  alloc(BB * 128 * 4);
  float* gate_sel = (float*)alloc(BB * 128 * 4);
  float* Wbuf     = (float*)alloc((size_t)4 * BB * FF * FF * 4); // 2 layers x pingpong
  float* pooled   = (float*)alloc((size_t)BB * 128 * FF * 4);
  float* hgbuf    = (float*)alloc((size_t)BB * 128 * FF * 4);
  float* gi       = (float*)alloc((size_t)BB * 128 * GG * 4);
  float* gh       = (float*)alloc((size_t)BB * 128 * GG * 4);
  float* act0     = (float*)alloc((size_t)BB * N * FF * 4);
  float* obuf     = (float*)alloc((size_t)BB * N * FF * 4);

  // ---- zero-init (ws is poisoned 0xAA before every timed call) ----
  hipMemsetAsync(deg, 0, (size_t)N * 4, stream);
  hipMemsetAsync(counts, 0, (size_t)N * 4, stream);
  hipMemsetAsync(cursors, 0, (size_t)N * 4, stream);
  hipMemsetAsync(flag, 0, 4, stream);
  hipMemsetAsync(keys, 0, (size_t)BB * KPAD * 8, stream);

  // ---- graph preprocessing ----
  detect_kernel<<<(E + 255) / 256, 256, 0, stream>>>((const int*)ei, E, flag);
  hist_kernel<<<(EN + 255) / 256, 256, 0, stream>>>(ei, flag, E, N, ew, deg, counts);
  dinv_kernel<<<(N + 255) / 256, 256, 0, stream>>>(deg, dinv, N);
  pnorm_kernel<<<2, 128, 0, stream>>>(p, pinv);
  scan_kernel<<<1, 1024, 0, stream>>>(counts, offsets, N, EN);
  scatter_kernel<<<(EN + 255) / 256, 256, 0, stream>>>(ei, flag, E, N, ew, dinv,
                                                       offsets, cursors, srt, wst);
  winit_kernel<<<(2 * BB * FF * FF + 255) / 256, 256, 0, stream>>>(W0, Wbuf);

  // W slabs: [layer][pingpong], each BB*FF*FF floats
  float* Wslab[2][2] = {
      {Wbuf, Wbuf + (size_t)BB * FF * FF},
      {Wbuf + (size_t)2 * BB * FF * FF, Wbuf + (size_t)3 * BB * FF * FF}};
  int cur[2] = {0, 0};

  for (int t = 0; t < TT; ++t) {
    for (int c = 0; c < 2; ++c) {
      const float* act; size_t bstride;
      if (c == 0) { act = x + (size_t)t * N * FF; bstride = (size_t)TT * N * FF; }
      else        { act = act0;                   bstride = (size_t)N * FF; }

      scores_kernel<<<dim3((N + 3) / 4, BB), 256, 0, stream>>>(
          act, bstride, p + c * FF, pinv + c, keys, N, KPAD);
      topk1_kernel<<<dim3(CH, BB), 256, 0, stream>>>(keys, cand, KPAD, NCAND);
      topk2_kernel<<<BB, 256, 0, stream>>>(cand, NCAND, idx_sel, gate_sel);
      gather_kernel<<<dim3(128, BB), 128, 0, stream>>>(
          act, bstride, Wslab[c][cur[c]], idx_sel, gate_sel, pooled, hgbuf);
      grugemm_kernel<<<dim3(BB, 4, 12), 256, 0, stream>>>(
          pooled, hgbuf, wih + (size_t)c * GG * FF, whh + (size_t)c * GG * FF,
          bih + c * GG, bhh + c * GG, gi, gh);
      grucomb_kernel<<<(BB * FF * FF + 255) / 256, 256, 0, stream>>>(
          gi, gh, hgbuf, Wslab[c][cur[c] ^ 1]);
      cur[c] ^= 1;

      // Layer-1 output is only consumed at the final timestep.
      if (c == 0 || t == TT - 1) {
        float* outp = (c == 0) ? act0 : (float*)d_out;
        gemm_kernel<<<dim3((N + 63) / 64, BB), 256, 0, stream>>>(
            act, bstride, Wslab[c][cur[c]], obuf, N);
        prop_kernel<<<dim3(N, BB), 128, 0, stream>>>(
            obuf, srt, wst, offsets, bias + c * FF, outp, N);
      }
    }
  }
}

// Round 2
// 2165.145 us; speedup vs baseline: 1.2960x; 1.2960x over previous
//
#include <hip/hip_runtime.h>
#include <hip/hip_bf16.h>
#include <math.h>

// EvolveGCN-H on MI355X. B=2, T=8, N=10000, F=DIN=DOUT=128, E=320000, 2 layers.
// R2: top-k via histogram radix-select + wave-level in-register bitonic
// (replaces 16x67us LDS bitonic sorts). prop fuses both batches per block.

#define BB 2
#define TT 8
#define FF 128
#define GG 384   // 3*FF
#define BINS 8192
#define CAP 512

// ---------------- edge fetch (int64 vs int32 runtime detect) ----------------
__global__ void detect_kernel(const int* ei32, int E, int* flag) {
  int e = blockIdx.x * 256 + threadIdx.x;
  if (e < E && ei32[2 * e + 1] != 0) atomicOr(flag, 1);
}

__device__ __forceinline__ void edge_fetch(const void* ei, int is32, int E,
                                           int e, const float* ew,
                                           int& row, int& col, float& w) {
  if (e < E) {
    if (is32) {
      const int* p = (const int*)ei;
      row = p[e]; col = p[E + e];
    } else {
      const long long* p = (const long long*)ei;
      row = (int)p[e]; col = (int)p[(long long)E + e];
    }
    w = ew[e];
  } else {           // self loop
    row = col = e - E; w = 1.0f;
  }
}

__global__ void hist_kernel(const void* ei, const int* flag, int E, int N,
                            const float* __restrict__ ew,
                            float* __restrict__ deg, int* __restrict__ counts) {
  int e = blockIdx.x * 256 + threadIdx.x;
  if (e >= E + N) return;
  int row, col; float w;
  edge_fetch(ei, *flag, E, e, ew, row, col, w);
  atomicAdd(&deg[col], w);
  atomicAdd(&counts[col], 1);
}

__global__ void dinv_kernel(const float* __restrict__ deg,
                            float* __restrict__ dinv, int N) {
  int n = blockIdx.x * 256 + threadIdx.x;
  if (n < N) { float d = deg[n]; dinv[n] = (d > 0.f) ? 1.0f / sqrtf(d) : 0.f; }
}

__global__ __launch_bounds__(1024) void scan_kernel(const int* __restrict__ counts,
                                                    int* __restrict__ offsets,
                                                    int N, int EN) {
  __shared__ int part[1024];
  int tid = threadIdx.x;
  int base = tid * 10;
  int lc[10]; int s = 0;
  for (int q = 0; q < 10; ++q) {
    int idx = base + q;
    int cv = (idx < N) ? counts[idx] : 0;
    lc[q] = cv; s += cv;
  }
  part[tid] = s;
  __syncthreads();
  for (int off = 1; off < 1024; off <<= 1) {
    int v = (tid >= off) ? part[tid - off] : 0;
    __syncthreads();
    part[tid] += v;
    __syncthreads();
  }
  int run = part[tid] - s;  // exclusive prefix
  for (int q = 0; q < 10; ++q) {
    int idx = base + q;
    if (idx < N) { offsets[idx] = run; run += lc[q]; }
  }
  if (tid == 0) offsets[N] = EN;
}

__global__ void scatter_kernel(const void* ei, const int* flag, int E, int N,
                               const float* __restrict__ ew,
                               const float* __restrict__ dinv,
                               const int* __restrict__ offs,
                               int* __restrict__ cursors,
                               int* __restrict__ srt, float* __restrict__ wst) {
  int e = blockIdx.x * 256 + threadIdx.x;
  if (e >= E + N) return;
  int row, col; float w;
  edge_fetch(ei, *flag, E, e, ew, row, col, w);
  int pos = atomicAdd(&cursors[col], 1);
  int slot = offs[col] + pos;
  srt[slot] = row;
  wst[slot] = dinv[row] * w * dinv[col];
}

// ---------------- misc setup ----------------
__global__ void winit_kernel(const float* __restrict__ W0, float* __restrict__ Wbuf) {
  int i = blockIdx.x * 256 + threadIdx.x;     // 2*2*16384 total
  if (i >= 2 * BB * FF * FF) return;
  int c = i >> 15;
  int rem = i & 32767;
  int e = rem & 16383;
  Wbuf[(size_t)c * 2 * BB * FF * FF + rem] = W0[c * FF * FF + e];
}

__global__ void pnorm_kernel(const float* __restrict__ p, float* __restrict__ pinv) {
  int c = blockIdx.x, tid = threadIdx.x;  // 128 threads
  float v = p[c * FF + tid];
  float s = v * v;
  for (int o = 32; o; o >>= 1) s += __shfl_xor(s, o, 64);
  __shared__ float red[2];
  if ((tid & 63) == 0) red[tid >> 6] = s;
  __syncthreads();
  if (tid == 0) pinv[c] = 1.0f / sqrtf(red[0] + red[1]);
}

// ---------------- scores + histogram ----------------
__global__ __launch_bounds__(256) void scores_hist_kernel(
    const float* __restrict__ act, size_t bstride,
    const float* __restrict__ p, const float* __restrict__ pinv,
    unsigned long long* __restrict__ keys, int* __restrict__ hist, int N) {
  int b = blockIdx.y;
  int wid = threadIdx.x >> 6, lane = threadIdx.x & 63;
  int n = blockIdx.x * 4 + wid;
  if (n >= N) return;
  const float2* row = (const float2*)(act + (size_t)b * bstride + (size_t)n * FF);
  const float2* p2 = (const float2*)p;
  float2 a = row[lane], pp = p2[lane];
  float s = a.x * pp.x + a.y * pp.y;
  for (int o = 32; o; o >>= 1) s += __shfl_xor(s, o, 64);
  if (lane == 0) {
    s *= *pinv;
    unsigned u = __float_as_uint(s);
    u = (u & 0x80000000u) ? ~u : (u | 0x80000000u);
    keys[(size_t)b * N + n] = ((unsigned long long)u << 32) | (unsigned)(~n);
    atomicAdd(&hist[b * BINS + (u >> 19)], 1);
  }
}

// ---------------- select threshold + filter + wave-register sort + emit -----
__device__ __forceinline__ unsigned long long shfl_xor_u64(unsigned long long x,
                                                           int m) {
  unsigned lo = (unsigned)x, hi = (unsigned)(x >> 32);
  lo = __shfl_xor(lo, m, 64);
  hi = __shfl_xor(hi, m, 64);
  return ((unsigned long long)hi << 32) | lo;
}

__global__ __launch_bounds__(1024) void selectsort_kernel(
    const unsigned long long* __restrict__ keys, int* __restrict__ hist,
    int N, int* __restrict__ idx_sel, float* __restrict__ gate_sel) {
  int b = blockIdx.x, tid = threadIdx.x;
  int* h = hist + b * BINS;
  __shared__ int part[1024];
  __shared__ unsigned long long cand[CAP];
  __shared__ int sT, ncnt;
  // local bin sums (8 bins/thread)
  int base = tid * 8;
  int lc[8]; int local = 0;
#pragma unroll
  for (int q = 0; q < 8; ++q) { lc[q] = h[base + q]; local += lc[q]; }
  if (tid == 0) ncnt = 0;
  part[tid] = local;
  __syncthreads();
  // inclusive suffix sum (Hillis-Steele, from high thread down)
  for (int off = 1; off < 1024; off <<= 1) {
    int v = (tid + off < 1024) ? part[tid + off] : 0;
    __syncthreads();
    part[tid] += v;
    __syncthreads();
  }
  int above = part[tid] - local;  // count in bins strictly above this range
  if (above < 128 && part[tid] >= 128) {
    int cnt = above;
#pragma unroll
    for (int q = 7; q >= 0; --q) {
      int c = lc[q];
      if (cnt + c >= 128) { sT = base + q; break; }
      cnt += c;
    }
  }
  __syncthreads();
  int T = sT;
  // zero histogram for next iteration (all reads done)
#pragma unroll
  for (int q = 0; q < 8; ++q) h[base + q] = 0;
  // filter candidates: bin >= T
  for (int i = tid; i < N; i += 1024) {
    unsigned long long kk = keys[(size_t)b * N + i];
    if ((int)(kk >> 51) >= T) {            // top 13 bits of key = bin
      int pos = atomicAdd(&ncnt, 1);
      if (pos < CAP) cand[pos] = kk;
    }
  }
  __syncthreads();
  // wave 0: in-register bitonic sort of 512 u64 (desc), zero barriers
  if (tid < 64) {
    int lane = tid;
    int nc = ncnt < CAP ? ncnt : CAP;
    unsigned long long v[8];
#pragma unroll
    for (int r = 0; r < 8; ++r) {
      int e = r * 64 + lane;
      v[r] = (e < nc) ? cand[e] : 0ULL;
    }
    for (int k = 2; k <= 512; k <<= 1)
      for (int j = k >> 1; j > 0; j >>= 1) {
        if (j >= 64) {
          int rj = j >> 6;
#pragma unroll
          for (int r = 0; r < 8; ++r)
            if (!(r & rj)) {
              int r2 = r | rj;
              bool up = (((r * 64) & k) != 0);
              unsigned long long a = v[r], c = v[r2];
              bool sw = up ? (a > c) : (a < c);
              if (sw) { v[r] = c; v[r2] = a; }
            }
        } else {
#pragma unroll
          for (int r = 0; r < 8; ++r) {
            unsigned long long o = shfl_xor_u64(v[r], j);
            int e = r * 64 + lane;
            bool up = (e & k) != 0;
            bool lower = (lane & j) == 0;
            unsigned long long mn = v[r] < o ? v[r] : o;
            unsigned long long mx = v[r] < o ? o : v[r];
            v[r] = (lower == up) ? mn : mx;
          }
        }
      }
    // emit top-128 (elements 0..127 = regs 0,1)
#pragma unroll
    for (int r = 0; r < 2; ++r) {
      int e = r * 64 + lane;
      unsigned long long kk = v[r];
      unsigned n = ~((unsigned)kk);
      unsigned u = (unsigned)(kk >> 32);
      float sc = (u & 0x80000000u) ? __uint_as_float(u & 0x7FFFFFFFu)
                                   : __uint_as_float(~u);
      idx_sel[b * 128 + e] = (int)n;
      gate_sel[b * 128 + e] = tanhf(sc);
    }
  }
}

// ---------------- GRU ----------------
__global__ __launch_bounds__(128) void gather_kernel(const float* __restrict__ act,
                                                     size_t bstride,
                                                     const float* __restrict__ Wcur,
                                                     const int* __restrict__ idx_sel,
                                                     const float* __restrict__ gate_sel,
                                                     float* __restrict__ pooled,
                                                     float* __restrict__ hgbuf) {
  int j = blockIdx.x, b = blockIdx.y, tid = threadIdx.x;
  int n = idx_sel[b * 128 + j];
  float g = gate_sel[b * 128 + j];
  pooled[((size_t)b * 128 + j) * FF + tid] =
      act[(size_t)b * bstride + (size_t)n * FF + tid] * g;
  hgbuf[((size_t)b * 128 + j) * FF + tid] =
      Wcur[((size_t)b * FF + tid) * FF + j];   // hg[j,k] = W[b,k,j]
}

__global__ __launch_bounds__(256) void grugemm_kernel(const float* __restrict__ pooled,
                                                      const float* __restrict__ hgbuf,
                                                      const float* __restrict__ wih,
                                                      const float* __restrict__ whh,
                                                      const float* __restrict__ bih,
                                                      const float* __restrict__ bhh,
                                                      float* __restrict__ gi,
                                                      float* __restrict__ gh) {
  int b = blockIdx.x, jt = blockIdx.y, gt = blockIdx.z;
  int jbase = jt * 32, gbase = gt * 32;
  __shared__ float sp[32][129], sh[32][129], sw[32][129];
  int tid = threadIdx.x;
  for (int e = tid; e < 32 * 128; e += 256) {
    int r = e >> 7, k = e & 127;
    sp[r][k] = pooled[((size_t)b * 128 + jbase + r) * FF + k];
    sh[r][k] = hgbuf[((size_t)b * 128 + jbase + r) * FF + k];
    sw[r][k] = wih[(gbase + r) * FF + k];
  }
  __syncthreads();
  int gl = tid & 31, jg = tid >> 5;  // jg in 0..7
  float acc[4] = {0.f, 0.f, 0.f, 0.f};
  for (int k = 0; k < 128; ++k) {
    float wv = sw[gl][k];
    acc[0] += sp[jg][k] * wv;
    acc[1] += sp[jg + 8][k] * wv;
    acc[2] += sp[jg + 16][k] * wv;
    acc[3] += sp[jg + 24][k] * wv;
  }
  float bi = bih[gbase + gl];
#pragma unroll
  for (int q = 0; q < 4; ++q)
    gi[((size_t)b * 128 + jbase + jg + q * 8) * GG + gbase + gl] = acc[q] + bi;
  __syncthreads();
  for (int e = tid; e < 32 * 128; e += 256) {
    int r = e >> 7, k = e & 127;
    sw[r][k] = whh[(gbase + r) * FF + k];
  }
  __syncthreads();
  float ac2[4] = {0.f, 0.f, 0.f, 0.f};
  for (int k = 0; k < 128; ++k) {
    float wv = sw[gl][k];
    ac2[0] += sh[jg][k] * wv;
    ac2[1] += sh[jg + 8][k] * wv;
    ac2[2] += sh[jg + 16][k] * wv;
    ac2[3] += sh[jg + 24][k] * wv;
  }
  float bh = bhh[gbase + gl];
#pragma unroll
  for (int q = 0; q < 4; ++q)
    gh[((size_t)b * 128 + jbase + jg + q * 8) * GG + gbase + gl] = ac2[q] + bh;
}

__global__ __launch_bounds__(256) void grucomb_kernel(const float* __restrict__ gi,
                                                      const float* __restrict__ gh,
                                                      const float* __restrict__ hgbuf,
                                                      float* __restrict__ Wnew) {
  int idx = blockIdx.x * 256 + threadIdx.x;   // BB*128*128
  if (idx >= BB * FF * FF) return;
  int b = idx >> 14;
  int r = idx & 16383;
  int k = r >> 7, j = r & 127;
  size_t base = ((size_t)b * 128 + j) * GG;
  float gir = gi[base + k], giz = gi[base + 128 + k], gin = gi[base + 256 + k];
  float ghr = gh[base + k], ghz = gh[base + 128 + k], ghn = gh[base + 256 + k];
  float rr = 1.0f / (1.0f + expf(-(gir + ghr)));
  float zz = 1.0f / (1.0f + expf(-(giz + ghz)));
  float nn = tanhf(gin + rr * ghn);
  float h = hgbuf[((size_t)b * 128 + j) * FF + k];
  float hnew = (1.0f - zz) * nn + zz * h;
  Wnew[((size_t)b * FF + k) * FF + j] = hnew;  // W[b,k,j] = newh[j,k]
}

// ---------------- dense GEMM: o[b,n,:] = act[b,n,:] @ W[b,:,:] ----------------
__global__ __launch_bounds__(256) void gemm_kernel(const float* __restrict__ act,
                                                   size_t bstride,
                                                   const float* __restrict__ W,
                                                   float* __restrict__ obuf, int N) {
  int nb = blockIdx.x, b = blockIdx.y;
  __shared__ float As[64][33];
  __shared__ float Bs[32][128];
  int tid = threadIdx.x;
  int tn = tid & 15, td = tid >> 4;
  float acc[4][8] = {};
  const float* Ab = act + (size_t)b * bstride;
  const float* Wb = W + (size_t)b * FF * FF;
  for (int kc = 0; kc < 4; ++kc) {
    int k0 = kc * 32;
    __syncthreads();
    for (int e = tid; e < 64 * 32; e += 256) {
      int r = e >> 5, kk = e & 31;
      int n = nb * 64 + r;
      As[r][kk] = (n < N) ? Ab[(size_t)n * FF + k0 + kk] : 0.f;
    }
    for (int e = tid; e < 32 * 128; e += 256) {
      int r = e >> 7, dd = e & 127;
      Bs[r][dd] = Wb[(k0 + r) * FF + dd];
    }
    __syncthreads();
    for (int kk = 0; kk < 32; ++kk) {
      float bv[8];
#pragma unroll
      for (int j = 0; j < 8; ++j) bv[j] = Bs[kk][td * 8 + j];
#pragma unroll
      for (int i = 0; i < 4; ++i) {
        float av = As[tn * 4 + i][kk];
#pragma unroll
        for (int j = 0; j < 8; ++j) acc[i][j] += av * bv[j];
      }
    }
  }
#pragma unroll
  for (int i = 0; i < 4; ++i) {
    int n = nb * 64 + tn * 4 + i;
    if (n < N) {
      float4* dst = (float4*)(obuf + ((size_t)b * N + n) * FF + td * 8);
      dst[0] = make_float4(acc[i][0], acc[i][1], acc[i][2], acc[i][3]);
      dst[1] = make_float4(acc[i][4], acc[i][5], acc[i][6], acc[i][7]);
    }
  }
}

// ---------------- CSR propagation + bias + relu (both batches/block) --------
__global__ __launch_bounds__(128) void prop_kernel(const float* __restrict__ o,
                                                   const int* __restrict__ srt,
                                                   const float* __restrict__ wst,
                                                   const int* __restrict__ offs,
                                                   const float* __restrict__ bias,
                                                   float* __restrict__ outp, int N) {
  int v = blockIdx.x, tid = threadIdx.x;
  int e0 = offs[v], e1 = offs[v + 1];
  __shared__ int ls[128];
  __shared__ float lw[128];
  float acc0 = 0.f, acc1 = 0.f;
  const float* ob0 = o;
  const float* ob1 = o + (size_t)N * FF;
  for (int base = e0; base < e1; base += 128) {
    int cnt = min(128, e1 - base);
    __syncthreads();
    if (tid < cnt) { ls[tid] = srt[base + tid]; lw[tid] = wst[base + tid]; }
    __syncthreads();
    for (int i = 0; i < cnt; ++i) {
      float wv = lw[i]; size_t roff = (size_t)ls[i] * FF + tid;
      acc0 += wv * ob0[roff];
      acc1 += wv * ob1[roff];
    }
  }
  float bv = bias[tid];
  outp[(size_t)v * FF + tid] = fmaxf(acc0 + bv, 0.f);
  outp[((size_t)N + v) * FF + tid] = fmaxf(acc1 + bv, 0.f);
}

// ---------------- host ----------------
extern "C" void kernel_launch(void* const* d_in, const int* in_sizes, int n_in,
                              void* d_out, int out_size, void* d_ws, size_t ws_size,
                              hipStream_t stream) {
  const float* x   = (const float*)d_in[0];
  const void*  ei  = d_in[1];
  const float* ew  = (const float*)d_in[2];
  const float* W0  = (const float*)d_in[3];
  const float* p   = (const float*)d_in[4];
  const float* wih = (const float*)d_in[5];
  const float* whh = (const float*)d_in[6];
  const float* bih = (const float*)d_in[7];
  const float* bhh = (const float*)d_in[8];
  const float* bias= (const float*)d_in[9];

  const int E  = in_sizes[2];
  const int N  = in_sizes[0] / (BB * TT * FF);
  const int EN = E + N;

  // ---- workspace carve (deterministic every call) ----
  char* w = (char*)d_ws;
  auto alloc = [&](size_t bytes) -> char* {
    char* r = w; w += (bytes + 255) & ~(size_t)255; return r;
  };
  float* deg      = (float*)alloc((size_t)N * 4);
  float* dinv     = (float*)alloc((size_t)N * 4);
  int*   counts   = (int*)  alloc((size_t)N * 4);
  int*   offsets  = (int*)  alloc((size_t)(N + 1) * 4);
  int*   cursors  = (int*)  alloc((size_t)N * 4);
  int*   flag     = (int*)  alloc(4);
  float* pinv     = (float*)alloc(2 * 4);
  int*   srt      = (int*)  alloc((size_t)EN * 4);
  float* wst      = (float*)alloc((size_t)EN * 4);
  unsigned long long* keys = (unsigned long long*)alloc((size_t)BB * N * 8);
  int*   hist     = (int*)  alloc((size_t)BB * BINS * 4);
  int*   idx_sel  = (int*)  alloc(BB * 128 * 4);
  float* gate_sel = (float*)alloc(BB * 128 * 4);
  float* Wbuf     = (float*)alloc((size_t)4 * BB * FF * FF * 4); // 2 layers x pingpong
  float* pooled   = (float*)alloc((size_t)BB * 128 * FF * 4);
  float* hgbuf    = (float*)alloc((size_t)BB * 128 * FF * 4);
  float* gi       = (float*)alloc((size_t)BB * 128 * GG * 4);
  float* gh       = (float*)alloc((size_t)BB * 128 * GG * 4);
  float* act0     = (float*)alloc((size_t)BB * N * FF * 4);
  float* obuf     = (float*)alloc((size_t)BB * N * FF * 4);

  // ---- zero-init (ws is poisoned 0xAA before every timed call) ----
  hipMemsetAsync(deg, 0, (size_t)N * 4, stream);
  hipMemsetAsync(counts, 0, (size_t)N * 4, stream);
  hipMemsetAsync(cursors, 0, (size_t)N * 4, stream);
  hipMemsetAsync(flag, 0, 4, stream);
  hipMemsetAsync(hist, 0, (size_t)BB * BINS * 4, stream);

  // ---- graph preprocessing ----
  detect_kernel<<<(E + 255) / 256, 256, 0, stream>>>((const int*)ei, E, flag);
  hist_kernel<<<(EN + 255) / 256, 256, 0, stream>>>(ei, flag, E, N, ew, deg, counts);
  dinv_kernel<<<(N + 255) / 256, 256, 0, stream>>>(deg, dinv, N);
  pnorm_kernel<<<2, 128, 0, stream>>>(p, pinv);
  scan_kernel<<<1, 1024, 0, stream>>>(counts, offsets, N, EN);
  scatter_kernel<<<(EN + 255) / 256, 256, 0, stream>>>(ei, flag, E, N, ew, dinv,
                                                       offsets, cursors, srt, wst);
  winit_kernel<<<(2 * BB * FF * FF + 255) / 256, 256, 0, stream>>>(W0, Wbuf);

  float* Wslab[2][2] = {
      {Wbuf, Wbuf + (size_t)BB * FF * FF},
      {Wbuf + (size_t)2 * BB * FF * FF, Wbuf + (size_t)3 * BB * FF * FF}};
  int cur[2] = {0, 0};

  for (int t = 0; t < TT; ++t) {
    for (int c = 0; c < 2; ++c) {
      const float* act; size_t bstride;
      if (c == 0) { act = x + (size_t)t * N * FF; bstride = (size_t)TT * N * FF; }
      else        { act = act0;                   bstride = (size_t)N * FF; }

      scores_hist_kernel<<<dim3((N + 3) / 4, BB), 256, 0, stream>>>(
          act, bstride, p + c * FF, pinv + c, keys, hist, N);
      selectsort_kernel<<<BB, 1024, 0, stream>>>(keys, hist, N, idx_sel, gate_sel);
      gather_kernel<<<dim3(128, BB), 128, 0, stream>>>(
          act, bstride, Wslab[c][cur[c]], idx_sel, gate_sel, pooled, hgbuf);
      grugemm_kernel<<<dim3(BB, 4, 12), 256, 0, stream>>>(
          pooled, hgbuf, wih + (size_t)c * GG * FF, whh + (size_t)c * GG * FF,
          bih + c * GG, bhh + c * GG, gi, gh);
      grucomb_kernel<<<(BB * FF * FF + 255) / 256, 256, 0, stream>>>(
          gi, gh, hgbuf, Wslab[c][cur[c] ^ 1]);
      cur[c] ^= 1;

      // Layer-1 output is only consumed at the final timestep.
      if (c == 0 || t == TT - 1) {
        float* outp = (c == 0) ? act0 : (float*)d_out;
        gemm_kernel<<<dim3((N + 63) / 64, BB), 256, 0, stream>>>(
            act, bstride, Wslab[c][cur[c]], obuf, N);
        prop_kernel<<<N, 128, 0, stream>>>(
            obuf, srt, wst, offsets, bias + c * FF, outp, N);
      }
    }
  }
}

// Round 3
// 2116.497 us; speedup vs baseline: 1.3258x; 1.0230x over previous
//
#include <hip/hip_runtime.h>
#include <hip/hip_bf16.h>
#include <math.h>

// EvolveGCN-H on MI355X. B=2, T=8, N=10000, F=DIN=DOUT=128, E=320000, 2 layers.
// R3: detect w/o atomic storm; selectsort scan via wave shuffles (1 barrier);
// GRU fused into one kernel (gather+gemm+gates); prop = wave-per-vertex,
// shuffle-broadcast metadata, no barriers.

#define BB 2
#define TT 8
#define FF 128
#define GG 384   // 3*FF
#define BINS 8192
#define CAP 512
#define WP 136   // padded LDS row stride for weight tiles (16B-aligned, 2-way max)

// ---------------- edge fetch (int64 vs int32 runtime detect) ----------------
__global__ void detect_kernel(const int* ei32, int E, int* flag) {
  // one block; sample 256 strided positions; plain store (no atomic storm)
  int step = E / 256;
  int e = threadIdx.x * step;
  if (ei32[2 * e + 1] != 0) *flag = 1;   // benign race, same value
}

__device__ __forceinline__ void edge_fetch(const void* ei, int is32, int E,
                                           int e, const float* ew,
                                           int& row, int& col, float& w) {
  if (e < E) {
    if (is32) {
      const int* p = (const int*)ei;
      row = p[e]; col = p[E + e];
    } else {
      const long long* p = (const long long*)ei;
      row = (int)p[e]; col = (int)p[(long long)E + e];
    }
    w = ew[e];
  } else {           // self loop
    row = col = e - E; w = 1.0f;
  }
}

__global__ void hist_kernel(const void* ei, const int* flag, int E, int N,
                            const float* __restrict__ ew,
                            float* __restrict__ deg, int* __restrict__ counts) {
  int e = blockIdx.x * 256 + threadIdx.x;
  if (e >= E + N) return;
  int row, col; float w;
  edge_fetch(ei, *flag, E, e, ew, row, col, w);
  atomicAdd(&deg[col], w);
  atomicAdd(&counts[col], 1);
}

__global__ void dinv_kernel(const float* __restrict__ deg,
                            float* __restrict__ dinv, int N) {
  int n = blockIdx.x * 256 + threadIdx.x;
  if (n < N) { float d = deg[n]; dinv[n] = (d > 0.f) ? 1.0f / sqrtf(d) : 0.f; }
}

__global__ __launch_bounds__(1024) void scan_kernel(const int* __restrict__ counts,
                                                    int* __restrict__ offsets,
                                                    int N, int EN) {
  __shared__ int part[1024];
  int tid = threadIdx.x;
  int base = tid * 10;
  int lc[10]; int s = 0;
  for (int q = 0; q < 10; ++q) {
    int idx = base + q;
    int cv = (idx < N) ? counts[idx] : 0;
    lc[q] = cv; s += cv;
  }
  part[tid] = s;
  __syncthreads();
  for (int off = 1; off < 1024; off <<= 1) {
    int v = (tid >= off) ? part[tid - off] : 0;
    __syncthreads();
    part[tid] += v;
    __syncthreads();
  }
  int run = part[tid] - s;  // exclusive prefix
  for (int q = 0; q < 10; ++q) {
    int idx = base + q;
    if (idx < N) { offsets[idx] = run; run += lc[q]; }
  }
  if (tid == 0) offsets[N] = EN;
}

__global__ void scatter_kernel(const void* ei, const int* flag, int E, int N,
                               const float* __restrict__ ew,
                               const float* __restrict__ dinv,
                               const int* __restrict__ offs,
                               int* __restrict__ cursors,
                               int* __restrict__ srt, float* __restrict__ wst) {
  int e = blockIdx.x * 256 + threadIdx.x;
  if (e >= E + N) return;
  int row, col; float w;
  edge_fetch(ei, *flag, E, e, ew, row, col, w);
  int pos = atomicAdd(&cursors[col], 1);
  int slot = offs[col] + pos;
  srt[slot] = row;
  wst[slot] = dinv[row] * w * dinv[col];
}

// ---------------- misc setup ----------------
__global__ void winit_kernel(const float* __restrict__ W0, float* __restrict__ Wbuf) {
  int i = blockIdx.x * 256 + threadIdx.x;     // 2*2*16384 total
  if (i >= 2 * BB * FF * FF) return;
  int c = i >> 15;
  int rem = i & 32767;
  int e = rem & 16383;
  Wbuf[(size_t)c * 2 * BB * FF * FF + rem] = W0[c * FF * FF + e];
}

__global__ void pnorm_kernel(const float* __restrict__ p, float* __restrict__ pinv) {
  int c = blockIdx.x, tid = threadIdx.x;  // 128 threads
  float v = p[c * FF + tid];
  float s = v * v;
  for (int o = 32; o; o >>= 1) s += __shfl_xor(s, o, 64);
  __shared__ float red[2];
  if ((tid & 63) == 0) red[tid >> 6] = s;
  __syncthreads();
  if (tid == 0) pinv[c] = 1.0f / sqrtf(red[0] + red[1]);
}

// ---------------- scores + histogram ----------------
__global__ __launch_bounds__(256) void scores_hist_kernel(
    const float* __restrict__ act, size_t bstride,
    const float* __restrict__ p, const float* __restrict__ pinv,
    unsigned long long* __restrict__ keys, int* __restrict__ hist, int N) {
  int b = blockIdx.y;
  int wid = threadIdx.x >> 6, lane = threadIdx.x & 63;
  int n = blockIdx.x * 4 + wid;
  if (n >= N) return;
  const float2* row = (const float2*)(act + (size_t)b * bstride + (size_t)n * FF);
  const float2* p2 = (const float2*)p;
  float2 a = row[lane], pp = p2[lane];
  float s = a.x * pp.x + a.y * pp.y;
  for (int o = 32; o; o >>= 1) s += __shfl_xor(s, o, 64);
  if (lane == 0) {
    s *= *pinv;
    unsigned u = __float_as_uint(s);
    u = (u & 0x80000000u) ? ~u : (u | 0x80000000u);
    keys[(size_t)b * N + n] = ((unsigned long long)u << 32) | (unsigned)(~n);
    atomicAdd(&hist[b * BINS + (u >> 19)], 1);
  }
}

// ---------------- select threshold + filter + wave-register sort + emit -----
__device__ __forceinline__ unsigned long long shfl_xor_u64(unsigned long long x,
                                                           int m) {
  unsigned lo = (unsigned)x, hi = (unsigned)(x >> 32);
  lo = __shfl_xor(lo, m, 64);
  hi = __shfl_xor(hi, m, 64);
  return ((unsigned long long)hi << 32) | lo;
}

__global__ __launch_bounds__(1024) void selectsort_kernel(
    const unsigned long long* __restrict__ keys, int* __restrict__ hist,
    int N, int* __restrict__ idx_sel, float* __restrict__ gate_sel) {
  int b = blockIdx.x, tid = threadIdx.x;
  int lane = tid & 63, wid = tid >> 6;   // 16 waves
  int* h = hist + b * BINS;
  __shared__ int wtot[16];
  __shared__ unsigned long long cand[CAP];
  __shared__ int sT, ncnt;
  // local bin sums (8 bins/thread)
  int base = tid * 8;
  int lc[8]; int local = 0;
#pragma unroll
  for (int q = 0; q < 8; ++q) { lc[q] = h[base + q]; local += lc[q]; }
  if (tid == 0) ncnt = 0;
  // wave-level inclusive suffix scan (sum over lanes >= lane)
  int s = local;
#pragma unroll
  for (int off = 1; off <= 32; off <<= 1) {
    int v = __shfl_down(s, off, 64);
    if (lane + off < 64) s += v;
  }
  if (lane == 0) wtot[wid] = s;   // wave total
  __syncthreads();
  int above_w = 0;
  for (int w2 = wid + 1; w2 < 16; ++w2) above_w += wtot[w2];
  int incl = above_w + s;          // suffix-inclusive over all higher threads
  int above = incl - local;        // strictly above this thread's 8 bins
  if (above < 128 && incl >= 128) {
    int cnt = above;
#pragma unroll
    for (int q = 7; q >= 0; --q) {
      int c = lc[q];
      if (cnt + c >= 128) { sT = base + q; break; }
      cnt += c;
    }
  }
  // zero own bins for next iteration (each thread zeros what it read)
#pragma unroll
  for (int q = 0; q < 8; ++q) h[base + q] = 0;
  __syncthreads();
  int T = sT;
  // filter candidates: bin >= T
  for (int i = tid; i < N; i += 1024) {
    unsigned long long kk = keys[(size_t)b * N + i];
    if ((int)(kk >> 51) >= T) {
      int pos = atomicAdd(&ncnt, 1);
      if (pos < CAP) cand[pos] = kk;
    }
  }
  __syncthreads();
  // wave 0: in-register bitonic sort of 512 u64 (desc), zero barriers
  if (tid < 64) {
    int nc = ncnt < CAP ? ncnt : CAP;
    unsigned long long v[8];
#pragma unroll
    for (int r = 0; r < 8; ++r) {
      int e = r * 64 + lane;
      v[r] = (e < nc) ? cand[e] : 0ULL;
    }
    for (int k = 2; k <= 512; k <<= 1)
      for (int j = k >> 1; j > 0; j >>= 1) {
        if (j >= 64) {
          int rj = j >> 6;
#pragma unroll
          for (int r = 0; r < 8; ++r)
            if (!(r & rj)) {
              int r2 = r | rj;
              bool up = (((r * 64) & k) != 0);
              unsigned long long a = v[r], c = v[r2];
              bool sw = up ? (a > c) : (a < c);
              if (sw) { v[r] = c; v[r2] = a; }
            }
        } else {
#pragma unroll
          for (int r = 0; r < 8; ++r) {
            unsigned long long o = shfl_xor_u64(v[r], j);
            int e = r * 64 + lane;
            bool up = (e & k) != 0;
            bool lower = (lane & j) == 0;
            unsigned long long mn = v[r] < o ? v[r] : o;
            unsigned long long mx = v[r] < o ? o : v[r];
            v[r] = (lower == up) ? mn : mx;
          }
        }
      }
#pragma unroll
    for (int r = 0; r < 2; ++r) {
      int e = r * 64 + lane;
      unsigned long long kk = v[r];
      unsigned n = ~((unsigned)kk);
      unsigned u = (unsigned)(kk >> 32);
      float sc = (u & 0x80000000u) ? __uint_as_float(u & 0x7FFFFFFFu)
                                   : __uint_as_float(~u);
      idx_sel[b * 128 + e] = (int)n;
      gate_sel[b * 128 + e] = tanhf(sc);
    }
  }
}

// ---------------- fused GRU: gather + both gemms + gates -> Wnew ------------
// grid (BB, 16 j-tiles of 8, 4 k-tiles of 32); 256 thr: kk=tid&31, jj=tid>>5
__global__ __launch_bounds__(256) void gru_kernel(
    const float* __restrict__ act, size_t bstride,
    const float* __restrict__ Wcur,
    const int* __restrict__ idx_sel, const float* __restrict__ gate_sel,
    const float* __restrict__ wih, const float* __restrict__ whh,
    const float* __restrict__ bih, const float* __restrict__ bhh,
    float* __restrict__ Wnew) {
  int b = blockIdx.x, j0 = blockIdx.y * 8, k0 = blockIdx.z * 32;
  int tid = threadIdx.x, kk = tid & 31, jj = tid >> 5;
  __shared__ float sp[8][FF], sh[8][FF];
  __shared__ float wtA[32][WP], wtB[32][WP];
  __shared__ int s_idx[8];
  __shared__ float s_gate[8];
  if (tid < 8) {
    s_idx[tid] = idx_sel[b * 128 + j0 + tid];
    s_gate[tid] = gate_sel[b * 128 + j0 + tid];
  }
  __syncthreads();
  for (int e = tid; e < 8 * FF; e += 256) {
    int j2 = e >> 7, m = e & 127;
    sp[j2][m] = act[(size_t)b * bstride + (size_t)s_idx[j2] * FF + m] * s_gate[j2];
    sh[j2][m] = Wcur[((size_t)b * FF + m) * FF + (j0 + j2)];
  }
  float accI[3], accH[3];
#pragma unroll
  for (int g = 0; g < 3; ++g) {
    __syncthreads();
    for (int e = tid; e < 32 * FF; e += 256) {
      int r = e >> 7, m = e & 127;
      wtA[r][m] = wih[(size_t)(g * FF + k0 + r) * FF + m];
      wtB[r][m] = whh[(size_t)(g * FF + k0 + r) * FF + m];
    }
    __syncthreads();
    float aI = 0.f, aH = 0.f;
    const float4* spv = (const float4*)sp[jj];
    const float4* shv = (const float4*)sh[jj];
    const float4* wav = (const float4*)wtA[kk];
    const float4* wbv = (const float4*)wtB[kk];
#pragma unroll 8
    for (int mq = 0; mq < 32; ++mq) {
      float4 a = spv[mq], hh = shv[mq], wa = wav[mq], wb = wbv[mq];
      aI += a.x * wa.x + a.y * wa.y + a.z * wa.z + a.w * wa.w;
      aH += hh.x * wb.x + hh.y * wb.y + hh.z * wb.z + hh.w * wb.w;
    }
    accI[g] = aI; accH[g] = aH;
  }
  int k = k0 + kk, j = j0 + jj;
  float gir = accI[0] + bih[k],        ghr = accH[0] + bhh[k];
  float giz = accI[1] + bih[FF + k],   ghz = accH[1] + bhh[FF + k];
  float gin = accI[2] + bih[2*FF + k], ghn = accH[2] + bhh[2*FF + k];
  float rr = 1.0f / (1.0f + expf(-(gir + ghr)));
  float zz = 1.0f / (1.0f + expf(-(giz + ghz)));
  float nn = tanhf(gin + rr * ghn);
  float h = sh[jj][k];
  float hnew = (1.0f - zz) * nn + zz * h;
  Wnew[((size_t)b * FF + k) * FF + j] = hnew;
}

// ---------------- dense GEMM: o[b,n,:] = act[b,n,:] @ W[b,:,:] ----------------
__global__ __launch_bounds__(256) void gemm_kernel(const float* __restrict__ act,
                                                   size_t bstride,
                                                   const float* __restrict__ W,
                                                   float* __restrict__ obuf, int N) {
  int nb = blockIdx.x, b = blockIdx.y;
  __shared__ float As[64][33];
  __shared__ float Bs[32][128];
  int tid = threadIdx.x;
  int tn = tid & 15, td = tid >> 4;
  float acc[4][8] = {};
  const float* Ab = act + (size_t)b * bstride;
  const float* Wb = W + (size_t)b * FF * FF;
  for (int kc = 0; kc < 4; ++kc) {
    int k0 = kc * 32;
    __syncthreads();
    for (int e = tid; e < 64 * 32; e += 256) {
      int r = e >> 5, kx = e & 31;
      int n = nb * 64 + r;
      As[r][kx] = (n < N) ? Ab[(size_t)n * FF + k0 + kx] : 0.f;
    }
    for (int e = tid; e < 32 * 128; e += 256) {
      int r = e >> 7, dd = e & 127;
      Bs[r][dd] = Wb[(k0 + r) * FF + dd];
    }
    __syncthreads();
    for (int kx = 0; kx < 32; ++kx) {
      float bv[8];
#pragma unroll
      for (int j = 0; j < 8; ++j) bv[j] = Bs[kx][td * 8 + j];
#pragma unroll
      for (int i = 0; i < 4; ++i) {
        float av = As[tn * 4 + i][kx];
#pragma unroll
        for (int j = 0; j < 8; ++j) acc[i][j] += av * bv[j];
      }
    }
  }
#pragma unroll
  for (int i = 0; i < 4; ++i) {
    int n = nb * 64 + tn * 4 + i;
    if (n < N) {
      float4* dst = (float4*)(obuf + ((size_t)b * N + n) * FF + td * 8);
      dst[0] = make_float4(acc[i][0], acc[i][1], acc[i][2], acc[i][3]);
      dst[1] = make_float4(acc[i][4], acc[i][5], acc[i][6], acc[i][7]);
    }
  }
}

// ------- CSR propagation + bias + relu: wave per vertex, both batches -------
__global__ __launch_bounds__(256) void prop_kernel(const float* __restrict__ o,
                                                   const int* __restrict__ srt,
                                                   const float* __restrict__ wst,
                                                   const int* __restrict__ offs,
                                                   const float* __restrict__ bias,
                                                   float* __restrict__ outp, int N) {
  int lane = threadIdx.x & 63;
  int v = blockIdx.x * 4 + (threadIdx.x >> 6);
  if (v >= N) return;
  int e0 = offs[v], e1 = offs[v + 1];
  const float2* ob0 = (const float2*)o;
  const float2* ob1 = (const float2*)(o + (size_t)N * FF);
  float2 acc0 = {0.f, 0.f}, acc1 = {0.f, 0.f};
  for (int base = e0; base < e1; base += 64) {
    int cnt = e1 - base; if (cnt > 64) cnt = 64;
    int sq = 0; float wq = 0.f;
    if (lane < cnt) { sq = srt[base + lane]; wq = wst[base + lane]; }
    for (int i = 0; i < cnt; ++i) {
      float wv = __shfl(wq, i, 64);
      int si = __shfl(sq, i, 64);
      size_t roff = (size_t)si * (FF / 2) + lane;
      float2 r0 = ob0[roff], r1 = ob1[roff];
      acc0.x += wv * r0.x; acc0.y += wv * r0.y;
      acc1.x += wv * r1.x; acc1.y += wv * r1.y;
    }
  }
  float2 bv = ((const float2*)bias)[lane];
  float2 o0 = {fmaxf(acc0.x + bv.x, 0.f), fmaxf(acc0.y + bv.y, 0.f)};
  float2 o1 = {fmaxf(acc1.x + bv.x, 0.f), fmaxf(acc1.y + bv.y, 0.f)};
  ((float2*)outp)[(size_t)v * (FF / 2) + lane] = o0;
  ((float2*)outp)[((size_t)N + v) * (FF / 2) + lane] = o1;
}

// ---------------- host ----------------
extern "C" void kernel_launch(void* const* d_in, const int* in_sizes, int n_in,
                              void* d_out, int out_size, void* d_ws, size_t ws_size,
                              hipStream_t stream) {
  const float* x   = (const float*)d_in[0];
  const void*  ei  = d_in[1];
  const float* ew  = (const float*)d_in[2];
  const float* W0  = (const float*)d_in[3];
  const float* p   = (const float*)d_in[4];
  const float* wih = (const float*)d_in[5];
  const float* whh = (const float*)d_in[6];
  const float* bih = (const float*)d_in[7];
  const float* bhh = (const float*)d_in[8];
  const float* bias= (const float*)d_in[9];

  const int E  = in_sizes[2];
  const int N  = in_sizes[0] / (BB * TT * FF);
  const int EN = E + N;

  // ---- workspace carve (deterministic every call) ----
  char* w = (char*)d_ws;
  auto alloc = [&](size_t bytes) -> char* {
    char* r = w; w += (bytes + 255) & ~(size_t)255; return r;
  };
  float* deg      = (float*)alloc((size_t)N * 4);
  float* dinv     = (float*)alloc((size_t)N * 4);
  int*   counts   = (int*)  alloc((size_t)N * 4);
  int*   offsets  = (int*)  alloc((size_t)(N + 1) * 4);
  int*   cursors  = (int*)  alloc((size_t)N * 4);
  int*   flag     = (int*)  alloc(4);
  float* pinv     = (float*)alloc(2 * 4);
  int*   srt      = (int*)  alloc((size_t)EN * 4);
  float* wst      = (float*)alloc((size_t)EN * 4);
  unsigned long long* keys = (unsigned long long*)alloc((size_t)BB * N * 8);
  int*   hist     = (int*)  alloc((size_t)BB * BINS * 4);
  int*   idx_sel  = (int*)  alloc(BB * 128 * 4);
  float* gate_sel = (float*)alloc(BB * 128 * 4);
  float* Wbuf     = (float*)alloc((size_t)4 * BB * FF * FF * 4); // 2 layers x pingpong
  float* act0     = (float*)alloc((size_t)BB * N * FF * 4);
  float* obuf     = (float*)alloc((size_t)BB * N * FF * 4);

  // ---- zero-init (ws is poisoned 0xAA before every timed call) ----
  hipMemsetAsync(deg, 0, (size_t)N * 4, stream);
  hipMemsetAsync(counts, 0, (size_t)N * 4, stream);
  hipMemsetAsync(cursors, 0, (size_t)N * 4, stream);
  hipMemsetAsync(flag, 0, 4, stream);
  hipMemsetAsync(hist, 0, (size_t)BB * BINS * 4, stream);

  // ---- graph preprocessing ----
  detect_kernel<<<1, 256, 0, stream>>>((const int*)ei, E, flag);
  hist_kernel<<<(EN + 255) / 256, 256, 0, stream>>>(ei, flag, E, N, ew, deg, counts);
  dinv_kernel<<<(N + 255) / 256, 256, 0, stream>>>(deg, dinv, N);
  pnorm_kernel<<<2, 128, 0, stream>>>(p, pinv);
  scan_kernel<<<1, 1024, 0, stream>>>(counts, offsets, N, EN);
  scatter_kernel<<<(EN + 255) / 256, 256, 0, stream>>>(ei, flag, E, N, ew, dinv,
                                                       offsets, cursors, srt, wst);
  winit_kernel<<<(2 * BB * FF * FF + 255) / 256, 256, 0, stream>>>(W0, Wbuf);

  float* Wslab[2][2] = {
      {Wbuf, Wbuf + (size_t)BB * FF * FF},
      {Wbuf + (size_t)2 * BB * FF * FF, Wbuf + (size_t)3 * BB * FF * FF}};
  int cur[2] = {0, 0};

  for (int t = 0; t < TT; ++t) {
    for (int c = 0; c < 2; ++c) {
      const float* act; size_t bstride;
      if (c == 0) { act = x + (size_t)t * N * FF; bstride = (size_t)TT * N * FF; }
      else        { act = act0;                   bstride = (size_t)N * FF; }

      scores_hist_kernel<<<dim3((N + 3) / 4, BB), 256, 0, stream>>>(
          act, bstride, p + c * FF, pinv + c, keys, hist, N);
      selectsort_kernel<<<BB, 1024, 0, stream>>>(keys, hist, N, idx_sel, gate_sel);
      gru_kernel<<<dim3(BB, 16, 4), 256, 0, stream>>>(
          act, bstride, Wslab[c][cur[c]], idx_sel, gate_sel,
          wih + (size_t)c * GG * FF, whh + (size_t)c * GG * FF,
          bih + c * GG, bhh + c * GG, Wslab[c][cur[c] ^ 1]);
      cur[c] ^= 1;

      // Layer-1 output is only consumed at the final timestep.
      if (c == 0 || t == TT - 1) {
        float* outp = (c == 0) ? act0 : (float*)d_out;
        gemm_kernel<<<dim3((N + 63) / 64, BB), 256, 0, stream>>>(
            act, bstride, Wslab[c][cur[c]], obuf, N);
        prop_kernel<<<(N + 3) / 4, 256, 0, stream>>>(
            obuf, srt, wst, offsets, bias + c * FF, outp, N);
      }
    }
  }
}

// Round 4
// 1046.853 us; speedup vs baseline: 2.6805x; 2.0218x over previous
//
#include <hip/hip_runtime.h>
#include <hip/hip_bf16.h>
#include <math.h>

// EvolveGCN-H on MI355X. B=2, T=8, N=10000, F=128, E=320000, 2 layers.
// R4: restructured dependency graph, 20 dispatches total.
//  - A(xW) = (Ax)W: batched prop on x upfront (independent of W evolution)
//  - per-j GRU independence: whole 8-step W chain in one kernel
//  - layer-1 scores fused into the batched GEMM epilogue

#define BB 2
#define TT 8
#define FF 128
#define GG 384   // 3*FF
#define BINS 8192
#define CAP 512

// ---------------- edge fetch (int64 vs int32 runtime detect) ----------------
__global__ void detect_kernel(const int* ei32, int E, int* flag) {
  int step = E / 256;
  int e = threadIdx.x * step;
  if (ei32[2 * e + 1] != 0) *flag = 1;   // benign race, same value
}

__device__ __forceinline__ void edge_fetch(const void* ei, int is32, int E,
                                           int e, const float* ew,
                                           int& row, int& col, float& w) {
  if (e < E) {
    if (is32) {
      const int* p = (const int*)ei;
      row = p[e]; col = p[E + e];
    } else {
      const long long* p = (const long long*)ei;
      row = (int)p[e]; col = (int)p[(long long)E + e];
    }
    w = ew[e];
  } else {           // self loop
    row = col = e - E; w = 1.0f;
  }
}

__global__ void hist_kernel(const void* ei, const int* flag, int E, int N,
                            const float* __restrict__ ew,
                            float* __restrict__ deg, int* __restrict__ counts) {
  int e = blockIdx.x * 256 + threadIdx.x;
  if (e >= E + N) return;
  int row, col; float w;
  edge_fetch(ei, *flag, E, e, ew, row, col, w);
  atomicAdd(&deg[col], w);
  atomicAdd(&counts[col], 1);
}

__global__ void dinv_kernel(const float* __restrict__ deg,
                            float* __restrict__ dinv, int N) {
  int n = blockIdx.x * 256 + threadIdx.x;
  if (n < N) { float d = deg[n]; dinv[n] = (d > 0.f) ? 1.0f / sqrtf(d) : 0.f; }
}

__global__ __launch_bounds__(1024) void scan_kernel(const int* __restrict__ counts,
                                                    int* __restrict__ offsets,
                                                    int N, int EN) {
  __shared__ int part[1024];
  int tid = threadIdx.x;
  int base = tid * 10;
  int lc[10]; int s = 0;
  for (int q = 0; q < 10; ++q) {
    int idx = base + q;
    int cv = (idx < N) ? counts[idx] : 0;
    lc[q] = cv; s += cv;
  }
  part[tid] = s;
  __syncthreads();
  for (int off = 1; off < 1024; off <<= 1) {
    int v = (tid >= off) ? part[tid - off] : 0;
    __syncthreads();
    part[tid] += v;
    __syncthreads();
  }
  int run = part[tid] - s;  // exclusive prefix
  for (int q = 0; q < 10; ++q) {
    int idx = base + q;
    if (idx < N) { offsets[idx] = run; run += lc[q]; }
  }
  if (tid == 0) offsets[N] = EN;
}

__global__ void scatter_kernel(const void* ei, const int* flag, int E, int N,
                               const float* __restrict__ ew,
                               const float* __restrict__ dinv,
                               const int* __restrict__ offs,
                               int* __restrict__ cursors,
                               int* __restrict__ srt, float* __restrict__ wst) {
  int e = blockIdx.x * 256 + threadIdx.x;
  if (e >= E + N) return;
  int row, col; float w;
  edge_fetch(ei, *flag, E, e, ew, row, col, w);
  int pos = atomicAdd(&cursors[col], 1);
  int slot = offs[col] + pos;
  srt[slot] = row;
  wst[slot] = dinv[row] * w * dinv[col];
}

__global__ void pnorm_kernel(const float* __restrict__ p, float* __restrict__ pinv) {
  int c = blockIdx.x, tid = threadIdx.x;  // 128 threads
  float v = p[c * FF + tid];
  float s = v * v;
  for (int o = 32; o; o >>= 1) s += __shfl_xor(s, o, 64);
  __shared__ float red[2];
  if ((tid & 63) == 0) red[tid >> 6] = s;
  __syncthreads();
  if (tid == 0) pinv[c] = 1.0f / sqrtf(red[0] + red[1]);
}

// ------- batched layer-0 scores over x: grid ((N+3)/4, 2b, 8t) -------------
__global__ __launch_bounds__(256) void scores_kernel(
    const float* __restrict__ x, const float* __restrict__ p,
    const float* __restrict__ pinv,
    unsigned long long* __restrict__ keys, int* __restrict__ hist, int N) {
  int b = blockIdx.y, t = blockIdx.z;
  int wid = threadIdx.x >> 6, lane = threadIdx.x & 63;
  int n = blockIdx.x * 4 + wid;
  if (n >= N) return;
  const float2* row = (const float2*)(x + (((size_t)b * TT + t) * N + n) * FF);
  const float2* p2 = (const float2*)p;
  float2 a = row[lane], pp = p2[lane];
  float s = a.x * pp.x + a.y * pp.y;
  for (int o = 32; o; o >>= 1) s += __shfl_xor(s, o, 64);
  if (lane == 0) {
    s *= *pinv;
    unsigned u = __float_as_uint(s);
    u = (u & 0x80000000u) ? ~u : (u | 0x80000000u);
    int tb = t * 2 + b;
    keys[(size_t)tb * N + n] = ((unsigned long long)u << 32) | (unsigned)(~n);
    atomicAdd(&hist[tb * BINS + (u >> 19)], 1);
  }
}

// ------- select threshold + filter + wave-register sort; grid (2b, 8t) -----
__device__ __forceinline__ unsigned long long shfl_xor_u64(unsigned long long x,
                                                           int m) {
  unsigned lo = (unsigned)x, hi = (unsigned)(x >> 32);
  lo = __shfl_xor(lo, m, 64);
  hi = __shfl_xor(hi, m, 64);
  return ((unsigned long long)hi << 32) | lo;
}

__global__ __launch_bounds__(1024) void selectsort_kernel(
    const unsigned long long* __restrict__ keys, const int* __restrict__ hist,
    int N, int* __restrict__ idx_sel, float* __restrict__ gate_sel) {
  int tb = blockIdx.y * 2 + blockIdx.x, tid = threadIdx.x;
  int lane = tid & 63, wid = tid >> 6;   // 16 waves
  const int* h = hist + tb * BINS;
  __shared__ int wtot[16];
  __shared__ unsigned long long cand[CAP];
  __shared__ int sT, ncnt;
  int base = tid * 8;
  int lc[8]; int local = 0;
#pragma unroll
  for (int q = 0; q < 8; ++q) { lc[q] = h[base + q]; local += lc[q]; }
  if (tid == 0) ncnt = 0;
  int s = local;
#pragma unroll
  for (int off = 1; off <= 32; off <<= 1) {
    int v = __shfl_down(s, off, 64);
    if (lane + off < 64) s += v;
  }
  if (lane == 0) wtot[wid] = s;
  __syncthreads();
  int above_w = 0;
  for (int w2 = wid + 1; w2 < 16; ++w2) above_w += wtot[w2];
  int incl = above_w + s;
  int above = incl - local;
  if (above < 128 && incl >= 128) {
    int cnt = above;
#pragma unroll
    for (int q = 7; q >= 0; --q) {
      int c = lc[q];
      if (cnt + c >= 128) { sT = base + q; break; }
      cnt += c;
    }
  }
  __syncthreads();
  int T = sT;
  for (int i = tid; i < N; i += 1024) {
    unsigned long long kk = keys[(size_t)tb * N + i];
    if ((int)(kk >> 51) >= T) {
      int pos = atomicAdd(&ncnt, 1);
      if (pos < CAP) cand[pos] = kk;
    }
  }
  __syncthreads();
  if (tid < 64) {
    int nc = ncnt < CAP ? ncnt : CAP;
    unsigned long long v[8];
#pragma unroll
    for (int r = 0; r < 8; ++r) {
      int e = r * 64 + lane;
      v[r] = (e < nc) ? cand[e] : 0ULL;
    }
    for (int k = 2; k <= 512; k <<= 1)
      for (int j = k >> 1; j > 0; j >>= 1) {
        if (j >= 64) {
          int rj = j >> 6;
#pragma unroll
          for (int r = 0; r < 8; ++r)
            if (!(r & rj)) {
              int r2 = r | rj;
              bool up = (((r * 64) & k) != 0);
              unsigned long long a = v[r], c = v[r2];
              bool sw = up ? (a > c) : (a < c);
              if (sw) { v[r] = c; v[r2] = a; }
            }
        } else {
#pragma unroll
          for (int r = 0; r < 8; ++r) {
            unsigned long long o = shfl_xor_u64(v[r], j);
            int e = r * 64 + lane;
            bool up = (e & k) != 0;
            bool lower = (lane & j) == 0;
            unsigned long long mn = v[r] < o ? v[r] : o;
            unsigned long long mx = v[r] < o ? o : v[r];
            v[r] = (lower == up) ? mn : mx;
          }
        }
      }
#pragma unroll
    for (int r = 0; r < 2; ++r) {
      int e = r * 64 + lane;
      unsigned long long kk = v[r];
      unsigned n = ~((unsigned)kk);
      unsigned u = (unsigned)(kk >> 32);
      float sc = (u & 0x80000000u) ? __uint_as_float(u & 0x7FFFFFFFu)
                                   : __uint_as_float(~u);
      idx_sel[tb * 128 + e] = (int)n;
      gate_sel[tb * 128 + e] = tanhf(sc);
    }
  }
}

// ------- whole W GRU chain (8 steps) in one kernel; grid (2b, 16 jtiles) ----
// per-j independence: h'[j,:] = GRUCell(pooled_t[j,:], h[j,:]).
// 256 thr: side = tid>>7 (0: gi from pooled, 1: gh from h), kl = tid&127.
__global__ __launch_bounds__(256) void wchain_kernel(
    const float* __restrict__ src, size_t src_tstride, size_t src_bstride,
    const int* __restrict__ idx_sel, const float* __restrict__ gate_sel,
    const float* __restrict__ Winit,   // [FF m][FF j]; h[j][m] = Winit[m][j]
    const float* __restrict__ wih, const float* __restrict__ whh,
    const float* __restrict__ bih, const float* __restrict__ bhh,
    float* __restrict__ snap) {        // [t*2+b][k][j]
  int b = blockIdx.x, j0 = blockIdx.y * 8;
  int tid = threadIdx.x, side = tid >> 7, kl = tid & 127;
  __shared__ float pooled[8][FF];
  __shared__ float hbuf[8][FF];
  __shared__ float ghbuf[3][8][FF];
  for (int e = tid; e < 8 * FF; e += 256) {
    int j = e >> 7, m = e & 127;
    hbuf[j][m] = Winit[m * FF + j0 + j];
  }
  float b0 = side ? bhh[kl] : bih[kl];
  float b1 = side ? bhh[FF + kl] : bih[FF + kl];
  float b2 = side ? bhh[2 * FF + kl] : bih[2 * FF + kl];
  const float* wmat = side ? whh : wih;
  const float4* w0p = (const float4*)(wmat + (size_t)(0 * FF + kl) * FF);
  const float4* w1p = (const float4*)(wmat + (size_t)(1 * FF + kl) * FF);
  const float4* w2p = (const float4*)(wmat + (size_t)(2 * FF + kl) * FF);
  for (int t = 0; t < TT; ++t) {
    int tb = t * 2 + b;
    __syncthreads();   // protects pooled overwrite + hbuf update visibility
    for (int e = tid; e < 8 * FF; e += 256) {
      int j = e >> 7, m = e & 127;
      int n = idx_sel[tb * 128 + j0 + j];
      float g = gate_sel[tb * 128 + j0 + j];
      pooled[j][m] =
          src[(size_t)t * src_tstride + (size_t)b * src_bstride +
              (size_t)n * FF + m] * g;
    }
    __syncthreads();
    const float4* vsrc = (const float4*)(side ? &hbuf[0][0] : &pooled[0][0]);
    float acc0[8] = {}, acc1[8] = {}, acc2[8] = {};
    for (int mq = 0; mq < 32; ++mq) {
      float4 w0 = w0p[mq], w1 = w1p[mq], w2 = w2p[mq];
#pragma unroll
      for (int j = 0; j < 8; ++j) {
        float4 v = vsrc[j * 32 + mq];
        acc0[j] += v.x * w0.x + v.y * w0.y + v.z * w0.z + v.w * w0.w;
        acc1[j] += v.x * w1.x + v.y * w1.y + v.z * w1.z + v.w * w1.w;
        acc2[j] += v.x * w2.x + v.y * w2.y + v.z * w2.z + v.w * w2.w;
      }
    }
    if (side) {
#pragma unroll
      for (int j = 0; j < 8; ++j) {
        ghbuf[0][j][kl] = acc0[j] + b0;
        ghbuf[1][j][kl] = acc1[j] + b1;
        ghbuf[2][j][kl] = acc2[j] + b2;
      }
    }
    __syncthreads();
    if (!side) {
#pragma unroll
      for (int j = 0; j < 8; ++j) {
        float rr = 1.0f / (1.0f + expf(-(acc0[j] + b0 + ghbuf[0][j][kl])));
        float zz = 1.0f / (1.0f + expf(-(acc1[j] + b1 + ghbuf[1][j][kl])));
        float nn = tanhf(acc2[j] + b2 + rr * ghbuf[2][j][kl]);
        float h = hbuf[j][kl];
        float hn = (1.0f - zz) * nn + zz * h;
        hbuf[j][kl] = hn;
        snap[((size_t)tb * FF + kl) * FF + j0 + j] = hn;
      }
    }
  }
}

// ------- batched GEMM + bias + relu (+ optional fused next-layer scores) ----
// out[tb][n][:] = relu(A[tb][n][:] @ Wsnap[tb] + bias); grid (ceil(N/128), 2b, Tz)
__global__ __launch_bounds__(256) void gemm_fused_kernel(
    const float* __restrict__ A, size_t a_tstride, size_t a_bstride,
    const float* __restrict__ Wsnap, const float* __restrict__ bias,
    float* __restrict__ out, size_t o_tstride, size_t o_bstride,
    const float* __restrict__ p1, const float* __restrict__ pinv1,
    unsigned long long* __restrict__ keys, int* __restrict__ hist, int N) {
  int nb = blockIdx.x, b = blockIdx.y, t = blockIdx.z;
  int tb = t * 2 + b;
  __shared__ float As[128][33];
  __shared__ float Bs[32][128];
  __shared__ float spart[128][17];
  __shared__ float p1s[128];
  int tid = threadIdx.x;
  int tc = tid & 15, tr = tid >> 4;
  if (p1 && tid < 128) p1s[tid] = p1[tid];
  float acc[8][8] = {};
  const float* Ab = A + (size_t)t * a_tstride + (size_t)b * a_bstride;
  const float* Wb = Wsnap + (size_t)tb * FF * FF;
  for (int kc = 0; kc < 4; ++kc) {
    int k0 = kc * 32;
    __syncthreads();
    for (int e = tid; e < 128 * 32; e += 256) {
      int r = e >> 5, kk = e & 31;
      int n = nb * 128 + r;
      As[r][kk] = (n < N) ? Ab[(size_t)n * FF + k0 + kk] : 0.f;
    }
    for (int e = tid; e < 32 * 128; e += 256) {
      int r = e >> 7, dd = e & 127;
      Bs[r][dd] = Wb[(k0 + r) * FF + dd];
    }
    __syncthreads();
    for (int kk = 0; kk < 32; ++kk) {
      float bv[8];
      const float4* brow = (const float4*)Bs[kk];
      float4 bq0 = brow[tc * 2], bq1 = brow[tc * 2 + 1];
      bv[0] = bq0.x; bv[1] = bq0.y; bv[2] = bq0.z; bv[3] = bq0.w;
      bv[4] = bq1.x; bv[5] = bq1.y; bv[6] = bq1.z; bv[7] = bq1.w;
#pragma unroll
      for (int i = 0; i < 8; ++i) {
        float av = As[tr * 8 + i][kk];
#pragma unroll
        for (int j = 0; j < 8; ++j) acc[i][j] += av * bv[j];
      }
    }
  }
  float bb[8];
#pragma unroll
  for (int j = 0; j < 8; ++j) bb[j] = bias[tc * 8 + j];
  float* ob = out + (size_t)t * o_tstride + (size_t)b * o_bstride;
#pragma unroll
  for (int i = 0; i < 8; ++i) {
    int n = nb * 128 + tr * 8 + i;
    float v[8]; float part = 0.f;
#pragma unroll
    for (int j = 0; j < 8; ++j) {
      v[j] = fmaxf(acc[i][j] + bb[j], 0.f);
      if (p1) part += v[j] * p1s[tc * 8 + j];
    }
    if (n < N) {
      float4* dst = (float4*)(ob + (size_t)n * FF + tc * 8);
      dst[0] = make_float4(v[0], v[1], v[2], v[3]);
      dst[1] = make_float4(v[4], v[5], v[6], v[7]);
    }
    if (p1) spart[tr * 8 + i][tc] = part;
  }
  if (p1) {
    __syncthreads();
    if (tid < 128) {
      int n = nb * 128 + tid;
      if (n < N) {
        float s = 0.f;
#pragma unroll
        for (int q = 0; q < 16; ++q) s += spart[tid][q];
        s *= *pinv1;
        unsigned u = __float_as_uint(s);
        u = (u & 0x80000000u) ? ~u : (u | 0x80000000u);
        keys[(size_t)tb * N + n] = ((unsigned long long)u << 32) | (unsigned)(~n);
        atomicAdd(&hist[tb * BINS + (u >> 19)], 1);
      }
    }
  }
}

// ------- CSR propagation (no bias/relu): wave/vertex, both b; grid (N/4, Tz) -
__global__ __launch_bounds__(256) void prop_kernel(
    const float* __restrict__ src, size_t s_tstride, size_t s_bstride,
    float* __restrict__ dst, size_t d_tstride, size_t d_bstride,
    const int* __restrict__ srt, const float* __restrict__ wst,
    const int* __restrict__ offs, int N) {
  int t = blockIdx.y;
  int lane = threadIdx.x & 63;
  int v = blockIdx.x * 4 + (threadIdx.x >> 6);
  if (v >= N) return;
  int e0 = offs[v], e1 = offs[v + 1];
  const float2* s0 = (const float2*)(src + (size_t)t * s_tstride);
  const float2* s1 = (const float2*)(src + (size_t)t * s_tstride + s_bstride);
  float2 acc0 = {0.f, 0.f}, acc1 = {0.f, 0.f};
  for (int base = e0; base < e1; base += 64) {
    int cnt = e1 - base; if (cnt > 64) cnt = 64;
    int sq = 0; float wq = 0.f;
    if (lane < cnt) { sq = srt[base + lane]; wq = wst[base + lane]; }
    for (int i = 0; i < cnt; ++i) {
      float wv = __shfl(wq, i, 64);
      int si = __shfl(sq, i, 64);
      size_t roff = (size_t)si * (FF / 2) + lane;
      float2 r0 = s0[roff], r1 = s1[roff];
      acc0.x += wv * r0.x; acc0.y += wv * r0.y;
      acc1.x += wv * r1.x; acc1.y += wv * r1.y;
    }
  }
  float2* d0 = (float2*)(dst + (size_t)t * d_tstride);
  float2* d1 = (float2*)(dst + (size_t)t * d_tstride + d_bstride);
  d0[(size_t)v * (FF / 2) + lane] = acc0;
  d1[(size_t)v * (FF / 2) + lane] = acc1;
}

// ---------------- host ----------------
extern "C" void kernel_launch(void* const* d_in, const int* in_sizes, int n_in,
                              void* d_out, int out_size, void* d_ws, size_t ws_size,
                              hipStream_t stream) {
  const float* x   = (const float*)d_in[0];
  const void*  ei  = d_in[1];
  const float* ew  = (const float*)d_in[2];
  const float* W0  = (const float*)d_in[3];
  const float* p   = (const float*)d_in[4];
  const float* wih = (const float*)d_in[5];
  const float* whh = (const float*)d_in[6];
  const float* bih = (const float*)d_in[7];
  const float* bhh = (const float*)d_in[8];
  const float* bias= (const float*)d_in[9];

  const int E  = in_sizes[2];
  const int N  = in_sizes[0] / (BB * TT * FF);
  const int EN = E + N;
  const size_t NF = (size_t)N * FF;

  char* w = (char*)d_ws;
  auto alloc = [&](size_t bytes) -> char* {
    char* r = w; w += (bytes + 255) & ~(size_t)255; return r;
  };
  float* deg      = (float*)alloc((size_t)N * 4);
  float* dinv     = (float*)alloc((size_t)N * 4);
  int*   counts   = (int*)  alloc((size_t)N * 4);
  int*   offsets  = (int*)  alloc((size_t)(N + 1) * 4);
  int*   cursors  = (int*)  alloc((size_t)N * 4);
  int*   flag     = (int*)  alloc(4);
  float* pinv     = (float*)alloc(2 * 4);
  int*   srt      = (int*)  alloc((size_t)EN * 4);
  float* wst      = (float*)alloc((size_t)EN * 4);
  unsigned long long* keys0 = (unsigned long long*)alloc((size_t)TT * BB * N * 8);
  unsigned long long* keys1 = (unsigned long long*)alloc((size_t)TT * BB * N * 8);
  int*   hist     = (int*)  alloc((size_t)2 * TT * BB * BINS * 4); // layer0|layer1
  int*   idx0     = (int*)  alloc((size_t)TT * BB * 128 * 4);
  float* gate0    = (float*)alloc((size_t)TT * BB * 128 * 4);
  int*   idx1     = (int*)  alloc((size_t)TT * BB * 128 * 4);
  float* gate1    = (float*)alloc((size_t)TT * BB * 128 * 4);
  float* W0snap   = (float*)alloc((size_t)TT * BB * FF * FF * 4);
  float* W1snap   = (float*)alloc((size_t)TT * BB * FF * FF * 4);
  float* xp       = (float*)alloc((size_t)TT * BB * NF * 4);  // A·x[t]
  float* act0     = (float*)alloc((size_t)TT * BB * NF * 4);  // layer-0 outputs
  float* xq       = (float*)alloc((size_t)BB * NF * 4);       // A·act0[7]
  int* hist0 = hist;
  int* hist1 = hist + (size_t)TT * BB * BINS;

  hipMemsetAsync(deg, 0, (size_t)N * 4, stream);
  hipMemsetAsync(counts, 0, (size_t)N * 4, stream);
  hipMemsetAsync(cursors, 0, (size_t)N * 4, stream);
  hipMemsetAsync(flag, 0, 4, stream);
  hipMemsetAsync(hist, 0, (size_t)2 * TT * BB * BINS * 4, stream);

  // graph preprocessing (CSR by destination + symmetric norm)
  detect_kernel<<<1, 256, 0, stream>>>((const int*)ei, E, flag);
  hist_kernel<<<(EN + 255) / 256, 256, 0, stream>>>(ei, flag, E, N, ew, deg, counts);
  dinv_kernel<<<(N + 255) / 256, 256, 0, stream>>>(deg, dinv, N);
  pnorm_kernel<<<2, 128, 0, stream>>>(p, pinv);
  scan_kernel<<<1, 1024, 0, stream>>>(counts, offsets, N, EN);
  scatter_kernel<<<(EN + 255) / 256, 256, 0, stream>>>(ei, flag, E, N, ew, dinv,
                                                       offsets, cursors, srt, wst);

  // xp[t][b] = A · x[b][t]   (all 8 t batched, independent of W)
  prop_kernel<<<dim3((N + 3) / 4, TT), 256, 0, stream>>>(
      x, NF, (size_t)TT * NF, xp, (size_t)BB * NF, NF, srt, wst, offsets, N);

  // layer-0 scores/select for all t (depend only on x)
  scores_kernel<<<dim3((N + 3) / 4, BB, TT), 256, 0, stream>>>(
      x, p, pinv, keys0, hist0, N);
  selectsort_kernel<<<dim3(BB, TT), 1024, 0, stream>>>(
      keys0, hist0, N, idx0, gate0);

  // whole layer-0 W chain (8 GRU steps) in one kernel
  wchain_kernel<<<dim3(BB, 16), 256, 0, stream>>>(
      x, NF, (size_t)TT * NF, idx0, gate0, W0,
      wih, whh, bih, bhh, W0snap);

  // act0[t][b] = relu(xp @ W0_t + bias0), fused layer-1 scores
  gemm_fused_kernel<<<dim3((N + 127) / 128, BB, TT), 256, 0, stream>>>(
      xp, (size_t)BB * NF, NF, W0snap, bias,
      act0, (size_t)BB * NF, NF,
      p + FF, pinv + 1, keys1, hist1, N);

  selectsort_kernel<<<dim3(BB, TT), 1024, 0, stream>>>(
      keys1, hist1, N, idx1, gate1);

  // layer-1 W chain
  wchain_kernel<<<dim3(BB, 16), 256, 0, stream>>>(
      act0, (size_t)BB * NF, NF, idx1, gate1, W0 + FF * FF,
      wih + (size_t)GG * FF, whh + (size_t)GG * FF,
      bih + GG, bhh + GG, W1snap);

  // xq[b] = A · act0[7][b]
  prop_kernel<<<dim3((N + 3) / 4, 1), 256, 0, stream>>>(
      act0 + (size_t)(TT - 1) * BB * NF, 0, NF, xq, 0, NF,
      srt, wst, offsets, N);

  // d_out = relu(xq @ W1_7 + bias1)
  gemm_fused_kernel<<<dim3((N + 127) / 128, BB, 1), 256, 0, stream>>>(
      xq, 0, NF, W1snap + (size_t)(TT - 1) * BB * FF * FF, bias + FF,
      (float*)d_out, 0, NF,
      nullptr, nullptr, nullptr, nullptr, N);
}

// Round 5
// 972.078 us; speedup vs baseline: 2.8867x; 1.0769x over previous
//
#include <hip/hip_runtime.h>
#include <hip/hip_bf16.h>
#include <math.h>

// EvolveGCN-H on MI355X. B=2, T=8, N=10000, F=128, E=320000, 2 layers.
// R5: scores fused into batched prop; packed int2 edge metadata; gemm with
// transposed-A b128 LDS reads; act0 in bf16 (downstream of all selections);
// shuffle-based scan; merged preprocessing; single zero-memset.

#define BB 2
#define TT 8
#define FF 128
#define GG 384   // 3*FF
#define BINS 8192
#define CAP 512

__device__ __forceinline__ float bf2f(unsigned short u) {
  return __uint_as_float((unsigned)u << 16);
}
__device__ __forceinline__ unsigned short f2bf(float f) {  // RNE
  unsigned x = __float_as_uint(f);
  unsigned r = ((x >> 16) & 1u) + 0x7fffu;
  return (unsigned short)((x + r) >> 16);
}

// ---------------- detect (int64 vs int32) + pnorm, one dispatch -------------
__global__ void prep_kernel(const int* __restrict__ ei32, int E, int* __restrict__ flag,
                            const float* __restrict__ p, float* __restrict__ pinv) {
  if (blockIdx.x == 0) {
    int step = E / 256;
    int e = threadIdx.x * step;
    if (ei32[2 * e + 1] != 0) *flag = 1;   // benign race, same value
  } else {
    int c = blockIdx.x - 1, tid = threadIdx.x;
    float s = 0.f;
    if (tid < 128) { float v = p[c * FF + tid]; s = v * v; }
    for (int o = 32; o; o >>= 1) s += __shfl_xor(s, o, 64);
    __shared__ float red[4];
    if ((tid & 63) == 0) red[tid >> 6] = s;
    __syncthreads();
    if (tid == 0) pinv[c] = 1.0f / sqrtf(red[0] + red[1] + red[2] + red[3]);
  }
}

__device__ __forceinline__ void edge_fetch(const void* ei, int is32, int E,
                                           int e, const float* ew,
                                           int& row, int& col, float& w) {
  if (e < E) {
    if (is32) {
      const int* p = (const int*)ei;
      row = p[e]; col = p[E + e];
    } else {
      const long long* p = (const long long*)ei;
      row = (int)p[e]; col = (int)p[(long long)E + e];
    }
    w = ew[e];
  } else {           // self loop
    row = col = e - E; w = 1.0f;
  }
}

__global__ void hist_kernel(const void* ei, const int* flag, int E, int N,
                            const float* __restrict__ ew,
                            float* __restrict__ deg, int* __restrict__ counts) {
  int e = blockIdx.x * 256 + threadIdx.x;
  if (e >= E + N) return;
  int row, col; float w;
  edge_fetch(ei, *flag, E, e, ew, row, col, w);
  atomicAdd(&deg[col], w);
  atomicAdd(&counts[col], 1);
}

// ---- offsets scan (shuffle-based, 1 barrier) + dinv, one dispatch ----------
__global__ __launch_bounds__(1024) void scan_kernel(
    const int* __restrict__ counts, const float* __restrict__ deg,
    int* __restrict__ offsets, float* __restrict__ dinv, int N, int EN) {
  __shared__ int wtot[16];
  int tid = threadIdx.x, lane = tid & 63, wid = tid >> 6;
  int base = tid * 10;
  int lc[10]; int s10 = 0;
#pragma unroll
  for (int q = 0; q < 10; ++q) {
    int idx = base + q;
    int cv = (idx < N) ? counts[idx] : 0;
    lc[q] = cv; s10 += cv;
    if (idx < N) {
      float d = deg[idx];
      dinv[idx] = (d > 0.f) ? 1.0f / sqrtf(d) : 0.f;
    }
  }
  int s = s10;
#pragma unroll
  for (int off = 1; off <= 32; off <<= 1) {
    int v = __shfl_up(s, off, 64);
    if (lane >= off) s += v;
  }
  if (lane == 63) wtot[wid] = s;
  __syncthreads();
  int pre = 0;
  for (int w2 = 0; w2 < wid; ++w2) pre += wtot[w2];
  int run = pre + s - s10;   // exclusive prefix
#pragma unroll
  for (int q = 0; q < 10; ++q) {
    int idx = base + q;
    if (idx < N) { offsets[idx] = run; run += lc[q]; }
  }
  if (tid == 0) offsets[N] = EN;
}

__global__ void scatter_kernel(const void* ei, const int* flag, int E, int N,
                               const float* __restrict__ ew,
                               const float* __restrict__ dinv,
                               const int* __restrict__ offs,
                               int* __restrict__ cursors,
                               int2* __restrict__ ep) {
  int e = blockIdx.x * 256 + threadIdx.x;
  if (e >= E + N) return;
  int row, col; float w;
  edge_fetch(ei, *flag, E, e, ew, row, col, w);
  int pos = atomicAdd(&cursors[col], 1);
  ep[offs[col] + pos] = make_int2(row, __float_as_int(dinv[row] * w * dinv[col]));
}

// ------- CSR prop, wave/vertex, both batches; optional fused scores ---------
// grid ((N+3)/4, T). Strides in float-element units.
template <int SRC_BF16>
__global__ __launch_bounds__(256) void prop_kernel(
    const void* __restrict__ srcv, size_t s_tstride, size_t s_bstride,
    float* __restrict__ dst, size_t d_tstride, size_t d_bstride,
    const int2* __restrict__ ep, const int* __restrict__ offs,
    const float* __restrict__ p, const float* __restrict__ pinv,
    unsigned long long* __restrict__ keys, int* __restrict__ hist, int N) {
  int t = blockIdx.y;
  int lane = threadIdx.x & 63;
  int v = blockIdx.x * 4 + (threadIdx.x >> 6);
  if (v >= N) return;
  int e0 = offs[v], e1 = offs[v + 1];
  size_t o0 = ((size_t)t * s_tstride) >> 1, o1 = o0 + (s_bstride >> 1);
  const float2* f0 = (const float2*)srcv + o0;
  const float2* f1 = (const float2*)srcv + o1;
  const ushort2* u0 = (const ushort2*)srcv + o0;
  const ushort2* u1 = (const ushort2*)srcv + o1;
  float2 acc0 = {0.f, 0.f}, acc1 = {0.f, 0.f};
  for (int base = e0; base < e1; base += 64) {
    int cnt = e1 - base; if (cnt > 64) cnt = 64;
    int2 m = make_int2(0, 0);
    if (lane < cnt) m = ep[base + lane];
    for (int i = 0; i < cnt; ++i) {
      int si = __shfl(m.x, i, 64);
      float wv = __int_as_float(__shfl(m.y, i, 64));
      size_t r = (size_t)si * 64 + lane;
      float2 x0, x1;
      if constexpr (SRC_BF16) {
        ushort2 a = u0[r], b = u1[r];
        x0 = make_float2(bf2f(a.x), bf2f(a.y));
        x1 = make_float2(bf2f(b.x), bf2f(b.y));
      } else {
        x0 = f0[r]; x1 = f1[r];
      }
      acc0.x += wv * x0.x; acc0.y += wv * x0.y;
      acc1.x += wv * x1.x; acc1.y += wv * x1.y;
    }
  }
  float2* d0 = (float2*)(dst + (size_t)t * d_tstride);
  float2* d1 = (float2*)(dst + (size_t)t * d_tstride + d_bstride);
  d0[(size_t)v * 64 + lane] = acc0;
  d1[(size_t)v * 64 + lane] = acc1;
  if constexpr (!SRC_BF16) {
    if (p) {   // fused layer-0 scores for both batches
      float2 pp = ((const float2*)p)[lane];
      float2 xv0 = f0[(size_t)v * 64 + lane], xv1 = f1[(size_t)v * 64 + lane];
      float sc0 = xv0.x * pp.x + xv0.y * pp.y;
      float sc1 = xv1.x * pp.x + xv1.y * pp.y;
      for (int o = 32; o; o >>= 1) {
        sc0 += __shfl_xor(sc0, o, 64);
        sc1 += __shfl_xor(sc1, o, 64);
      }
      if (lane == 0) {
        float piv = *pinv;
        float ss[2] = {sc0 * piv, sc1 * piv};
#pragma unroll
        for (int b = 0; b < 2; ++b) {
          unsigned u = __float_as_uint(ss[b]);
          u = (u & 0x80000000u) ? ~u : (u | 0x80000000u);
          int tb = t * 2 + b;
          keys[(size_t)tb * N + v] =
              ((unsigned long long)u << 32) | (unsigned)(~v);
          atomicAdd(&hist[tb * BINS + (u >> 19)], 1);
        }
      }
    }
  }
}

// ------- select threshold + filter + wave-register sort; grid (2b, 8t) -----
__device__ __forceinline__ unsigned long long shfl_xor_u64(unsigned long long x,
                                                           int m) {
  unsigned lo = (unsigned)x, hi = (unsigned)(x >> 32);
  lo = __shfl_xor(lo, m, 64);
  hi = __shfl_xor(hi, m, 64);
  return ((unsigned long long)hi << 32) | lo;
}

__global__ __launch_bounds__(1024) void selectsort_kernel(
    const unsigned long long* __restrict__ keys, const int* __restrict__ hist,
    int N, int* __restrict__ idx_sel, float* __restrict__ gate_sel) {
  int tb = blockIdx.y * 2 + blockIdx.x, tid = threadIdx.x;
  int lane = tid & 63, wid = tid >> 6;   // 16 waves
  const int* h = hist + tb * BINS;
  __shared__ int wtot[16];
  __shared__ unsigned long long cand[CAP];
  __shared__ int sT, ncnt;
  int base = tid * 8;
  int lc[8]; int local = 0;
#pragma unroll
  for (int q = 0; q < 8; ++q) { lc[q] = h[base + q]; local += lc[q]; }
  if (tid == 0) ncnt = 0;
  int s = local;
#pragma unroll
  for (int off = 1; off <= 32; off <<= 1) {
    int v = __shfl_down(s, off, 64);
    if (lane + off < 64) s += v;
  }
  if (lane == 0) wtot[wid] = s;
  __syncthreads();
  int above_w = 0;
  for (int w2 = wid + 1; w2 < 16; ++w2) above_w += wtot[w2];
  int incl = above_w + s;
  int above = incl - local;
  if (above < 128 && incl >= 128) {
    int cnt = above;
#pragma unroll
    for (int q = 7; q >= 0; --q) {
      int c = lc[q];
      if (cnt + c >= 128) { sT = base + q; break; }
      cnt += c;
    }
  }
  __syncthreads();
  int T = sT;
  for (int i = tid; i < N; i += 1024) {
    unsigned long long kk = keys[(size_t)tb * N + i];
    if ((int)(kk >> 51) >= T) {
      int pos = atomicAdd(&ncnt, 1);
      if (pos < CAP) cand[pos] = kk;
    }
  }
  __syncthreads();
  if (tid < 64) {
    int nc = ncnt < CAP ? ncnt : CAP;
    unsigned long long v[8];
#pragma unroll
    for (int r = 0; r < 8; ++r) {
      int e = r * 64 + lane;
      v[r] = (e < nc) ? cand[e] : 0ULL;
    }
    for (int k = 2; k <= 512; k <<= 1)
      for (int j = k >> 1; j > 0; j >>= 1) {
        if (j >= 64) {
          int rj = j >> 6;
#pragma unroll
          for (int r = 0; r < 8; ++r)
            if (!(r & rj)) {
              int r2 = r | rj;
              bool up = (((r * 64) & k) != 0);
              unsigned long long a = v[r], c = v[r2];
              bool sw = up ? (a > c) : (a < c);
              if (sw) { v[r] = c; v[r2] = a; }
            }
        } else {
#pragma unroll
          for (int r = 0; r < 8; ++r) {
            unsigned long long o = shfl_xor_u64(v[r], j);
            int e = r * 64 + lane;
            bool up = (e & k) != 0;
            bool lower = (lane & j) == 0;
            unsigned long long mn = v[r] < o ? v[r] : o;
            unsigned long long mx = v[r] < o ? o : v[r];
            v[r] = (lower == up) ? mn : mx;
          }
        }
      }
#pragma unroll
    for (int r = 0; r < 2; ++r) {
      int e = r * 64 + lane;
      unsigned long long kk = v[r];
      unsigned n = ~((unsigned)kk);
      unsigned u = (unsigned)(kk >> 32);
      float sc = (u & 0x80000000u) ? __uint_as_float(u & 0x7FFFFFFFu)
                                   : __uint_as_float(~u);
      idx_sel[tb * 128 + e] = (int)n;
      gate_sel[tb * 128 + e] = tanhf(sc);
    }
  }
}

// ------- whole W GRU chain (8 steps) in one kernel; grid (2b, 16 jtiles) ----
template <int SRC_BF16>
__global__ __launch_bounds__(256) void wchain_kernel(
    const void* __restrict__ srcv, size_t src_tstride, size_t src_bstride,
    const int* __restrict__ idx_sel, const float* __restrict__ gate_sel,
    const float* __restrict__ Winit,   // [FF m][FF j]; h[j][m] = Winit[m][j]
    const float* __restrict__ wih, const float* __restrict__ whh,
    const float* __restrict__ bih, const float* __restrict__ bhh,
    float* __restrict__ snap) {        // [t*2+b][k][j]
  int b = blockIdx.x, j0 = blockIdx.y * 8;
  int tid = threadIdx.x, side = tid >> 7, kl = tid & 127;
  __shared__ float pooled[8][FF];
  __shared__ float hbuf[8][FF];
  __shared__ float ghbuf[3][8][FF];
  for (int e = tid; e < 8 * FF; e += 256) {
    int j = e >> 7, m = e & 127;
    hbuf[j][m] = Winit[m * FF + j0 + j];
  }
  float b0 = side ? bhh[kl] : bih[kl];
  float b1 = side ? bhh[FF + kl] : bih[FF + kl];
  float b2 = side ? bhh[2 * FF + kl] : bih[2 * FF + kl];
  const float* wmat = side ? whh : wih;
  const float4* w0p = (const float4*)(wmat + (size_t)(0 * FF + kl) * FF);
  const float4* w1p = (const float4*)(wmat + (size_t)(1 * FF + kl) * FF);
  const float4* w2p = (const float4*)(wmat + (size_t)(2 * FF + kl) * FF);
  for (int t = 0; t < TT; ++t) {
    int tb = t * 2 + b;
    __syncthreads();   // protects pooled overwrite + hbuf update visibility
    for (int e = tid; e < 8 * FF; e += 256) {
      int j = e >> 7, m = e & 127;
      int n = idx_sel[tb * 128 + j0 + j];
      float g = gate_sel[tb * 128 + j0 + j];
      size_t off = (size_t)t * src_tstride + (size_t)b * src_bstride +
                   (size_t)n * FF + m;
      float xv;
      if constexpr (SRC_BF16) xv = bf2f(((const unsigned short*)srcv)[off]);
      else                    xv = ((const float*)srcv)[off];
      pooled[j][m] = xv * g;
    }
    __syncthreads();
    const float4* vsrc = (const float4*)(side ? &hbuf[0][0] : &pooled[0][0]);
    float acc0[8] = {}, acc1[8] = {}, acc2[8] = {};
    for (int mq = 0; mq < 32; ++mq) {
      float4 w0 = w0p[mq], w1 = w1p[mq], w2 = w2p[mq];
#pragma unroll
      for (int j = 0; j < 8; ++j) {
        float4 v = vsrc[j * 32 + mq];
        acc0[j] += v.x * w0.x + v.y * w0.y + v.z * w0.z + v.w * w0.w;
        acc1[j] += v.x * w1.x + v.y * w1.y + v.z * w1.z + v.w * w1.w;
        acc2[j] += v.x * w2.x + v.y * w2.y + v.z * w2.z + v.w * w2.w;
      }
    }
    if (side) {
#pragma unroll
      for (int j = 0; j < 8; ++j) {
        ghbuf[0][j][kl] = acc0[j] + b0;
        ghbuf[1][j][kl] = acc1[j] + b1;
        ghbuf[2][j][kl] = acc2[j] + b2;
      }
    }
    __syncthreads();
    if (!side) {
#pragma unroll
      for (int j = 0; j < 8; ++j) {
        float rr = 1.0f / (1.0f + expf(-(acc0[j] + b0 + ghbuf[0][j][kl])));
        float zz = 1.0f / (1.0f + expf(-(acc1[j] + b1 + ghbuf[1][j][kl])));
        float nn = tanhf(acc2[j] + b2 + rr * ghbuf[2][j][kl]);
        float h = hbuf[j][kl];
        float hn = (1.0f - zz) * nn + zz * h;
        hbuf[j][kl] = hn;
        snap[((size_t)tb * FF + kl) * FF + j0 + j] = hn;
      }
    }
  }
}

// ------- batched GEMM + bias + relu (+ optional fused next-layer scores) ----
// out[tb][n][:] = relu(A[tb][n][:] @ Wsnap[tb] + bias); grid (ceil(N/128), 2b, Tz)
// Output: fp32 (outf) or bf16 (outb) — exactly one non-null.
__global__ __launch_bounds__(256) void gemm_kernel(
    const float* __restrict__ A, size_t a_tstride, size_t a_bstride,
    const float* __restrict__ Wsnap, const float* __restrict__ bias,
    float* __restrict__ outf, unsigned short* __restrict__ outb,
    size_t o_tstride, size_t o_bstride,
    const float* __restrict__ p1, const float* __restrict__ pinv1,
    unsigned long long* __restrict__ keys, int* __restrict__ hist, int N) {
  int nb = blockIdx.x, b = blockIdx.y, t = blockIdx.z;
  int tb = t * 2 + b;
  __shared__ float Ast[32][132];   // transposed: [kk][row]
  __shared__ float Bs[32][128];
  __shared__ float spart[128][17];
  __shared__ float p1s[128];
  int tid = threadIdx.x;
  int tc = tid & 15, tr = tid >> 4;
  if (p1 && tid < 128) p1s[tid] = p1[tid];
  float acc[8][8] = {};
  const float* Ab = A + (size_t)t * a_tstride + (size_t)b * a_bstride;
  const float* Wb = Wsnap + (size_t)tb * FF * FF;
  for (int kc = 0; kc < 4; ++kc) {
    int k0 = kc * 32;
    __syncthreads();
    for (int e = tid; e < 128 * 32; e += 256) {
      int r = e >> 5, kk = e & 31;
      int n = nb * 128 + r;
      Ast[kk][r] = (n < N) ? Ab[(size_t)n * FF + k0 + kk] : 0.f;
    }
    for (int e = tid; e < 32 * 128; e += 256) {
      int r = e >> 7, dd = e & 127;
      Bs[r][dd] = Wb[(k0 + r) * FF + dd];
    }
    __syncthreads();
#pragma unroll 4
    for (int kk = 0; kk < 32; ++kk) {
      const float4* arow = (const float4*)Ast[kk];
      float4 a0 = arow[tr * 2], a1 = arow[tr * 2 + 1];
      const float4* brow = (const float4*)Bs[kk];
      float4 b0 = brow[tc * 2], b1 = brow[tc * 2 + 1];
      float av[8] = {a0.x, a0.y, a0.z, a0.w, a1.x, a1.y, a1.z, a1.w};
      float bv[8] = {b0.x, b0.y, b0.z, b0.w, b1.x, b1.y, b1.z, b1.w};
#pragma unroll
      for (int i = 0; i < 8; ++i)
#pragma unroll
        for (int j = 0; j < 8; ++j) acc[i][j] += av[i] * bv[j];
    }
  }
  float bb[8];
#pragma unroll
  for (int j = 0; j < 8; ++j) bb[j] = bias[tc * 8 + j];
  size_t obase = (size_t)t * o_tstride + (size_t)b * o_bstride;
#pragma unroll
  for (int i = 0; i < 8; ++i) {
    int n = nb * 128 + tr * 8 + i;
    float v[8]; float part = 0.f;
#pragma unroll
    for (int j = 0; j < 8; ++j) {
      v[j] = fmaxf(acc[i][j] + bb[j], 0.f);
      if (p1) part += v[j] * p1s[tc * 8 + j];
    }
    if (n < N) {
      if (outb) {
        unsigned short* dst = outb + obase + (size_t)n * FF + tc * 8;
        uint4 pk;
        pk.x = (unsigned)f2bf(v[0]) | ((unsigned)f2bf(v[1]) << 16);
        pk.y = (unsigned)f2bf(v[2]) | ((unsigned)f2bf(v[3]) << 16);
        pk.z = (unsigned)f2bf(v[4]) | ((unsigned)f2bf(v[5]) << 16);
        pk.w = (unsigned)f2bf(v[6]) | ((unsigned)f2bf(v[7]) << 16);
        *(uint4*)dst = pk;
      } else {
        float4* dst = (float4*)(outf + obase + (size_t)n * FF + tc * 8);
        dst[0] = make_float4(v[0], v[1], v[2], v[3]);
        dst[1] = make_float4(v[4], v[5], v[6], v[7]);
      }
    }
    if (p1) spart[tr * 8 + i][tc] = part;
  }
  if (p1) {
    __syncthreads();
    if (tid < 128) {
      int n = nb * 128 + tid;
      if (n < N) {
        float s = 0.f;
#pragma unroll
        for (int q = 0; q < 16; ++q) s += spart[tid][q];
        s *= *pinv1;
        unsigned u = __float_as_uint(s);
        u = (u & 0x80000000u) ? ~u : (u | 0x80000000u);
        keys[(size_t)tb * N + n] = ((unsigned long long)u << 32) | (unsigned)(~n);
        atomicAdd(&hist[tb * BINS + (u >> 19)], 1);
      }
    }
  }
}

// ---------------- host ----------------
extern "C" void kernel_launch(void* const* d_in, const int* in_sizes, int n_in,
                              void* d_out, int out_size, void* d_ws, size_t ws_size,
                              hipStream_t stream) {
  const float* x   = (const float*)d_in[0];
  const void*  ei  = d_in[1];
  const float* ew  = (const float*)d_in[2];
  const float* W0  = (const float*)d_in[3];
  const float* p   = (const float*)d_in[4];
  const float* wih = (const float*)d_in[5];
  const float* whh = (const float*)d_in[6];
  const float* bih = (const float*)d_in[7];
  const float* bhh = (const float*)d_in[8];
  const float* bias= (const float*)d_in[9];

  const int E  = in_sizes[2];
  const int N  = in_sizes[0] / (BB * TT * FF);
  const int EN = E + N;
  const size_t NF = (size_t)N * FF;

  char* w = (char*)d_ws;
  auto alloc = [&](size_t bytes) -> char* {
    char* r = w; w += (bytes + 255) & ~(size_t)255; return r;
  };
  // ---- zero region (single memset) ----
  char* zbeg = w;
  float* deg      = (float*)alloc((size_t)N * 4);
  int*   counts   = (int*)  alloc((size_t)N * 4);
  int*   cursors  = (int*)  alloc((size_t)N * 4);
  int*   flag     = (int*)  alloc(4);
  int*   hist     = (int*)  alloc((size_t)2 * TT * BB * BINS * 4);
  char* zend = w;
  // ---- rest ----
  int*   offsets  = (int*)  alloc((size_t)(N + 1) * 4);
  float* dinv     = (float*)alloc((size_t)N * 4);
  float* pinv     = (float*)alloc(2 * 4);
  int2*  ep       = (int2*) alloc((size_t)EN * 8);
  unsigned long long* keys0 = (unsigned long long*)alloc((size_t)TT * BB * N * 8);
  unsigned long long* keys1 = (unsigned long long*)alloc((size_t)TT * BB * N * 8);
  int*   idx0     = (int*)  alloc((size_t)TT * BB * 128 * 4);
  float* gate0    = (float*)alloc((size_t)TT * BB * 128 * 4);
  int*   idx1     = (int*)  alloc((size_t)TT * BB * 128 * 4);
  float* gate1    = (float*)alloc((size_t)TT * BB * 128 * 4);
  float* W0snap   = (float*)alloc((size_t)TT * BB * FF * FF * 4);
  float* W1snap   = (float*)alloc((size_t)TT * BB * FF * FF * 4);
  float* xp       = (float*)alloc((size_t)TT * BB * NF * 4);  // A·x[t], fp32
  unsigned short* act0 = (unsigned short*)alloc((size_t)TT * BB * NF * 2); // bf16
  float* xq       = (float*)alloc((size_t)BB * NF * 4);       // A·act0[7], fp32
  int* hist0 = hist;
  int* hist1 = hist + (size_t)TT * BB * BINS;

  hipMemsetAsync(zbeg, 0, (size_t)(zend - zbeg), stream);

  // graph preprocessing (CSR by destination + symmetric norm)
  prep_kernel<<<3, 256, 0, stream>>>((const int*)ei, E, flag, p, pinv);
  hist_kernel<<<(EN + 255) / 256, 256, 0, stream>>>(ei, flag, E, N, ew, deg, counts);
  scan_kernel<<<1, 1024, 0, stream>>>(counts, deg, offsets, dinv, N, EN);
  scatter_kernel<<<(EN + 255) / 256, 256, 0, stream>>>(ei, flag, E, N, ew, dinv,
                                                       offsets, cursors, ep);

  // xp[t][b] = A · x[b][t] for all t, with fused layer-0 scores
  prop_kernel<0><<<dim3((N + 3) / 4, TT), 256, 0, stream>>>(
      x, NF, (size_t)TT * NF, xp, (size_t)BB * NF, NF,
      ep, offsets, p, pinv, keys0, hist0, N);

  selectsort_kernel<<<dim3(BB, TT), 1024, 0, stream>>>(
      keys0, hist0, N, idx0, gate0);

  // whole layer-0 W chain (8 GRU steps)
  wchain_kernel<0><<<dim3(BB, 16), 256, 0, stream>>>(
      x, NF, (size_t)TT * NF, idx0, gate0, W0,
      wih, whh, bih, bhh, W0snap);

  // act0[t][b] = relu(xp @ W0_t + bias0) -> bf16, fused layer-1 scores (fp32)
  gemm_kernel<<<dim3((N + 127) / 128, BB, TT), 256, 0, stream>>>(
      xp, (size_t)BB * NF, NF, W0snap, bias,
      nullptr, act0, (size_t)BB * NF, NF,
      p + FF, pinv + 1, keys1, hist1, N);

  selectsort_kernel<<<dim3(BB, TT), 1024, 0, stream>>>(
      keys1, hist1, N, idx1, gate1);

  // layer-1 W chain (bf16 pooled gathers)
  wchain_kernel<1><<<dim3(BB, 16), 256, 0, stream>>>(
      act0, (size_t)BB * NF, NF, idx1, gate1, W0 + FF * FF,
      wih + (size_t)GG * FF, whh + (size_t)GG * FF,
      bih + GG, bhh + GG, W1snap);

  // xq[b] = A · act0[7][b]  (bf16 gather, fp32 accumulate)
  prop_kernel<1><<<dim3((N + 3) / 4, 1), 256, 0, stream>>>(
      act0 + (size_t)(TT - 1) * BB * NF, 0, NF, xq, 0, NF,
      ep, offsets, nullptr, nullptr, nullptr, nullptr, N);

  // d_out = relu(xq @ W1_7 + bias1), fp32
  gemm_kernel<<<dim3((N + 127) / 128, BB, 1), 256, 0, stream>>>(
      xq, 0, NF, W1snap + (size_t)(TT - 1) * BB * FF * FF, bias + FF,
      (float*)d_out, nullptr, 0, NF,
      nullptr, nullptr, nullptr, nullptr, N);
}

// Round 7
// 919.333 us; speedup vs baseline: 3.0524x; 1.0574x over previous
//
#include <hip/hip_runtime.h>
#include <hip/hip_bf16.h>
#include <math.h>

// EvolveGCN-H on MI355X. B=2, T=8, N=10000, F=128, E=320000, 2 layers.
// R7 = R6 with compile fix: nontemporal store via native ext_vector_type
// (HIP float4* is a class type the builtin rejects).
// R6: prop restructured for MLP (2 edges x 2 batches of float4 loads in
// flight per lane, halves merged via shfl_xor(32)); nontemporal xp stores;
// wchain j-tile 4 (2x blocks). Selection-critical fp32 paths unchanged.

#define BB 2
#define TT 8
#define FF 128
#define GG 384   // 3*FF
#define BINS 8192
#define CAP 512

typedef float v4f __attribute__((ext_vector_type(4)));

__device__ __forceinline__ float bf2f(unsigned short u) {
  return __uint_as_float((unsigned)u << 16);
}
__device__ __forceinline__ unsigned short f2bf(float f) {  // RNE
  unsigned x = __float_as_uint(f);
  unsigned r = ((x >> 16) & 1u) + 0x7fffu;
  return (unsigned short)((x + r) >> 16);
}
__device__ __forceinline__ float4 bf4(ushort4 u) {
  return make_float4(bf2f(u.x), bf2f(u.y), bf2f(u.z), bf2f(u.w));
}

// ---------------- detect (int64 vs int32) + pnorm, one dispatch -------------
__global__ void prep_kernel(const int* __restrict__ ei32, int E, int* __restrict__ flag,
                            const float* __restrict__ p, float* __restrict__ pinv) {
  if (blockIdx.x == 0) {
    int step = E / 256;
    int e = threadIdx.x * step;
    if (ei32[2 * e + 1] != 0) *flag = 1;   // benign race, same value
  } else {
    int c = blockIdx.x - 1, tid = threadIdx.x;
    float s = 0.f;
    if (tid < 128) { float v = p[c * FF + tid]; s = v * v; }
    for (int o = 32; o; o >>= 1) s += __shfl_xor(s, o, 64);
    __shared__ float red[4];
    if ((tid & 63) == 0) red[tid >> 6] = s;
    __syncthreads();
    if (tid == 0) pinv[c] = 1.0f / sqrtf(red[0] + red[1] + red[2] + red[3]);
  }
}

__device__ __forceinline__ void edge_fetch(const void* ei, int is32, int E,
                                           int e, const float* ew,
                                           int& row, int& col, float& w) {
  if (e < E) {
    if (is32) {
      const int* p = (const int*)ei;
      row = p[e]; col = p[E + e];
    } else {
      const long long* p = (const long long*)ei;
      row = (int)p[e]; col = (int)p[(long long)E + e];
    }
    w = ew[e];
  } else {           // self loop
    row = col = e - E; w = 1.0f;
  }
}

__global__ void hist_kernel(const void* ei, const int* flag, int E, int N,
                            const float* __restrict__ ew,
                            float* __restrict__ deg, int* __restrict__ counts) {
  int e = blockIdx.x * 256 + threadIdx.x;
  if (e >= E + N) return;
  int row, col; float w;
  edge_fetch(ei, *flag, E, e, ew, row, col, w);
  atomicAdd(&deg[col], w);
  atomicAdd(&counts[col], 1);
}

// ---- offsets scan (shuffle-based, 1 barrier) + dinv, one dispatch ----------
__global__ __launch_bounds__(1024) void scan_kernel(
    const int* __restrict__ counts, const float* __restrict__ deg,
    int* __restrict__ offsets, float* __restrict__ dinv, int N, int EN) {
  __shared__ int wtot[16];
  int tid = threadIdx.x, lane = tid & 63, wid = tid >> 6;
  int base = tid * 10;
  int lc[10]; int s10 = 0;
#pragma unroll
  for (int q = 0; q < 10; ++q) {
    int idx = base + q;
    int cv = (idx < N) ? counts[idx] : 0;
    lc[q] = cv; s10 += cv;
    if (idx < N) {
      float d = deg[idx];
      dinv[idx] = (d > 0.f) ? 1.0f / sqrtf(d) : 0.f;
    }
  }
  int s = s10;
#pragma unroll
  for (int off = 1; off <= 32; off <<= 1) {
    int v = __shfl_up(s, off, 64);
    if (lane >= off) s += v;
  }
  if (lane == 63) wtot[wid] = s;
  __syncthreads();
  int pre = 0;
  for (int w2 = 0; w2 < wid; ++w2) pre += wtot[w2];
  int run = pre + s - s10;   // exclusive prefix
#pragma unroll
  for (int q = 0; q < 10; ++q) {
    int idx = base + q;
    if (idx < N) { offsets[idx] = run; run += lc[q]; }
  }
  if (tid == 0) offsets[N] = EN;
}

__global__ void scatter_kernel(const void* ei, const int* flag, int E, int N,
                               const float* __restrict__ ew,
                               const float* __restrict__ dinv,
                               const int* __restrict__ offs,
                               int* __restrict__ cursors,
                               int2* __restrict__ ep) {
  int e = blockIdx.x * 256 + threadIdx.x;
  if (e >= E + N) return;
  int row, col; float w;
  edge_fetch(ei, *flag, E, e, ew, row, col, w);
  int pos = atomicAdd(&cursors[col], 1);
  ep[offs[col] + pos] = make_int2(row, __float_as_int(dinv[row] * w * dinv[col]));
}

// ------- CSR prop, wave/vertex, both batches; optional fused scores ---------
// grid ((N+3)/4, T). Strides in source-element units (float or bf16).
// Lane layout: half = edge parity, sub = float4 index in the 128-wide row.
template <int SRC_BF16>
__global__ __launch_bounds__(256) void prop_kernel(
    const void* __restrict__ srcv, size_t s_tstride, size_t s_bstride,
    float* __restrict__ dst, size_t d_tstride, size_t d_bstride,
    const int2* __restrict__ ep, const int* __restrict__ offs,
    const float* __restrict__ p, const float* __restrict__ pinv,
    unsigned long long* __restrict__ keys, int* __restrict__ hist, int N) {
  int t = blockIdx.y;
  int lane = threadIdx.x & 63;
  int half = lane >> 5, sub = lane & 31;
  int v = blockIdx.x * 4 + (threadIdx.x >> 6);
  if (v >= N) return;
  int e0 = offs[v], e1 = offs[v + 1];
  size_t o0 = (size_t)t * s_tstride, o1 = o0 + s_bstride;
  const float4* f0 = (const float4*)srcv + (o0 >> 2);
  const float4* f1 = (const float4*)srcv + (o1 >> 2);
  const ushort4* u0 = (const ushort4*)srcv + (o0 >> 2);
  const ushort4* u1 = (const ushort4*)srcv + (o1 >> 2);
  float4 acc0 = {0.f, 0.f, 0.f, 0.f}, acc1 = {0.f, 0.f, 0.f, 0.f};
  for (int base = e0; base < e1; base += 64) {
    int cnt = e1 - base; if (cnt > 64) cnt = 64;
    int2 m = make_int2(0, 0);
    if (lane < cnt) m = ep[base + lane];
    for (int i = 0; i < cnt; i += 4) {
      int i0 = i + half, i1 = i + 2 + half;
      int sA = __shfl(m.x, i0, 64);
      float wA = __int_as_float(__shfl(m.y, i0, 64));
      int sB = __shfl(m.x, i1, 64);
      float wB = __int_as_float(__shfl(m.y, i1, 64));
      if (i0 >= cnt) wA = 0.f;
      if (i1 >= cnt) wB = 0.f;
      size_t rA = (size_t)sA * 32 + sub, rB = (size_t)sB * 32 + sub;
      float4 a0, a1, b0, b1;
      if constexpr (SRC_BF16) {
        a0 = bf4(u0[rA]); a1 = bf4(u1[rA]);
        b0 = bf4(u0[rB]); b1 = bf4(u1[rB]);
      } else {
        a0 = f0[rA]; a1 = f1[rA];
        b0 = f0[rB]; b1 = f1[rB];
      }
      acc0.x += wA * a0.x + wB * b0.x;  acc0.y += wA * a0.y + wB * b0.y;
      acc0.z += wA * a0.z + wB * b0.z;  acc0.w += wA * a0.w + wB * b0.w;
      acc1.x += wA * a1.x + wB * b1.x;  acc1.y += wA * a1.y + wB * b1.y;
      acc1.z += wA * a1.z + wB * b1.z;  acc1.w += wA * a1.w + wB * b1.w;
    }
  }
  // merge edge-parity halves
  acc0.x += __shfl_xor(acc0.x, 32, 64); acc0.y += __shfl_xor(acc0.y, 32, 64);
  acc0.z += __shfl_xor(acc0.z, 32, 64); acc0.w += __shfl_xor(acc0.w, 32, 64);
  acc1.x += __shfl_xor(acc1.x, 32, 64); acc1.y += __shfl_xor(acc1.y, 32, 64);
  acc1.z += __shfl_xor(acc1.z, 32, 64); acc1.w += __shfl_xor(acc1.w, 32, 64);
  if (half == 0) {
    v4f* d0 = (v4f*)((float4*)(dst + (size_t)t * d_tstride) +
                     (size_t)v * 32 + sub);
    v4f* d1 = (v4f*)((float4*)(dst + (size_t)t * d_tstride + d_bstride) +
                     (size_t)v * 32 + sub);
    v4f s0 = {acc0.x, acc0.y, acc0.z, acc0.w};
    v4f s1 = {acc1.x, acc1.y, acc1.z, acc1.w};
    __builtin_nontemporal_store(s0, d0);
    __builtin_nontemporal_store(s1, d1);
  }
  if constexpr (!SRC_BF16) {
    if (p) {   // fused layer-0 scores: half 0 -> batch 0, half 1 -> batch 1
      float4 xv = (half ? f1 : f0)[(size_t)v * 32 + sub];
      float4 pp = ((const float4*)p)[sub];
      float sc = xv.x * pp.x + xv.y * pp.y + xv.z * pp.z + xv.w * pp.w;
#pragma unroll
      for (int o = 1; o <= 16; o <<= 1) sc += __shfl_xor(sc, o, 64);
      if (sub == 0) {
        float ss = sc * (*pinv);
        unsigned u = __float_as_uint(ss);
        u = (u & 0x80000000u) ? ~u : (u | 0x80000000u);
        int tb = t * 2 + half;
        keys[(size_t)tb * N + v] = ((unsigned long long)u << 32) | (unsigned)(~v);
        atomicAdd(&hist[tb * BINS + (u >> 19)], 1);
      }
    }
  }
}

// ------- select threshold + filter + wave-register sort; grid (2b, 8t) -----
__device__ __forceinline__ unsigned long long shfl_xor_u64(unsigned long long x,
                                                           int m) {
  unsigned lo = (unsigned)x, hi = (unsigned)(x >> 32);
  lo = __shfl_xor(lo, m, 64);
  hi = __shfl_xor(hi, m, 64);
  return ((unsigned long long)hi << 32) | lo;
}

__global__ __launch_bounds__(1024) void selectsort_kernel(
    const unsigned long long* __restrict__ keys, const int* __restrict__ hist,
    int N, int* __restrict__ idx_sel, float* __restrict__ gate_sel) {
  int tb = blockIdx.y * 2 + blockIdx.x, tid = threadIdx.x;
  int lane = tid & 63, wid = tid >> 6;   // 16 waves
  const int* h = hist + tb * BINS;
  __shared__ int wtot[16];
  __shared__ unsigned long long cand[CAP];
  __shared__ int sT, ncnt;
  int base = tid * 8;
  int lc[8]; int local = 0;
#pragma unroll
  for (int q = 0; q < 8; ++q) { lc[q] = h[base + q]; local += lc[q]; }
  if (tid == 0) ncnt = 0;
  int s = local;
#pragma unroll
  for (int off = 1; off <= 32; off <<= 1) {
    int v = __shfl_down(s, off, 64);
    if (lane + off < 64) s += v;
  }
  if (lane == 0) wtot[wid] = s;
  __syncthreads();
  int above_w = 0;
  for (int w2 = wid + 1; w2 < 16; ++w2) above_w += wtot[w2];
  int incl = above_w + s;
  int above = incl - local;
  if (above < 128 && incl >= 128) {
    int cnt = above;
#pragma unroll
    for (int q = 7; q >= 0; --q) {
      int c = lc[q];
      if (cnt + c >= 128) { sT = base + q; break; }
      cnt += c;
    }
  }
  __syncthreads();
  int T = sT;
  for (int i = tid; i < N; i += 1024) {
    unsigned long long kk = keys[(size_t)tb * N + i];
    if ((int)(kk >> 51) >= T) {
      int pos = atomicAdd(&ncnt, 1);
      if (pos < CAP) cand[pos] = kk;
    }
  }
  __syncthreads();
  if (tid < 64) {
    int nc = ncnt < CAP ? ncnt : CAP;
    unsigned long long v[8];
#pragma unroll
    for (int r = 0; r < 8; ++r) {
      int e = r * 64 + lane;
      v[r] = (e < nc) ? cand[e] : 0ULL;
    }
    for (int k = 2; k <= 512; k <<= 1)
      for (int j = k >> 1; j > 0; j >>= 1) {
        if (j >= 64) {
          int rj = j >> 6;
#pragma unroll
          for (int r = 0; r < 8; ++r)
            if (!(r & rj)) {
              int r2 = r | rj;
              bool up = (((r * 64) & k) != 0);
              unsigned long long a = v[r], c = v[r2];
              bool sw = up ? (a > c) : (a < c);
              if (sw) { v[r] = c; v[r2] = a; }
            }
        } else {
#pragma unroll
          for (int r = 0; r < 8; ++r) {
            unsigned long long o = shfl_xor_u64(v[r], j);
            int e = r * 64 + lane;
            bool up = (e & k) != 0;
            bool lower = (lane & j) == 0;
            unsigned long long mn = v[r] < o ? v[r] : o;
            unsigned long long mx = v[r] < o ? o : v[r];
            v[r] = (lower == up) ? mn : mx;
          }
        }
      }
#pragma unroll
    for (int r = 0; r < 2; ++r) {
      int e = r * 64 + lane;
      unsigned long long kk = v[r];
      unsigned n = ~((unsigned)kk);
      unsigned u = (unsigned)(kk >> 32);
      float sc = (u & 0x80000000u) ? __uint_as_float(u & 0x7FFFFFFFu)
                                   : __uint_as_float(~u);
      idx_sel[tb * 128 + e] = (int)n;
      gate_sel[tb * 128 + e] = tanhf(sc);
    }
  }
}

// ------- whole W GRU chain (8 steps) in one kernel; grid (2b, 32 jtiles) ----
template <int SRC_BF16>
__global__ __launch_bounds__(256) void wchain_kernel(
    const void* __restrict__ srcv, size_t src_tstride, size_t src_bstride,
    const int* __restrict__ idx_sel, const float* __restrict__ gate_sel,
    const float* __restrict__ Winit,   // [FF m][FF j]; h[j][m] = Winit[m][j]
    const float* __restrict__ wih, const float* __restrict__ whh,
    const float* __restrict__ bih, const float* __restrict__ bhh,
    float* __restrict__ snap) {        // [t*2+b][k][j]
  int b = blockIdx.x, j0 = blockIdx.y * 4;
  int tid = threadIdx.x, side = tid >> 7, kl = tid & 127;
  __shared__ float pooled[4][FF];
  __shared__ float hbuf[4][FF];
  __shared__ float ghbuf[3][4][FF];
  for (int e = tid; e < 4 * FF; e += 256) {
    int j = e >> 7, m = e & 127;
    hbuf[j][m] = Winit[m * FF + j0 + j];
  }
  float b0 = side ? bhh[kl] : bih[kl];
  float b1 = side ? bhh[FF + kl] : bih[FF + kl];
  float b2 = side ? bhh[2 * FF + kl] : bih[2 * FF + kl];
  const float* wmat = side ? whh : wih;
  const float4* w0p = (const float4*)(wmat + (size_t)(0 * FF + kl) * FF);
  const float4* w1p = (const float4*)(wmat + (size_t)(1 * FF + kl) * FF);
  const float4* w2p = (const float4*)(wmat + (size_t)(2 * FF + kl) * FF);
  for (int t = 0; t < TT; ++t) {
    int tb = t * 2 + b;
    __syncthreads();   // protects pooled overwrite + hbuf update visibility
    for (int e = tid; e < 4 * FF; e += 256) {
      int j = e >> 7, m = e & 127;
      int n = idx_sel[tb * 128 + j0 + j];
      float g = gate_sel[tb * 128 + j0 + j];
      size_t off = (size_t)t * src_tstride + (size_t)b * src_bstride +
                   (size_t)n * FF + m;
      float xv;
      if constexpr (SRC_BF16) xv = bf2f(((const unsigned short*)srcv)[off]);
      else                    xv = ((const float*)srcv)[off];
      pooled[j][m] = xv * g;
    }
    __syncthreads();
    const float4* vsrc = (const float4*)(side ? &hbuf[0][0] : &pooled[0][0]);
    float acc0[4] = {}, acc1[4] = {}, acc2[4] = {};
    for (int mq = 0; mq < 32; ++mq) {
      float4 w0 = w0p[mq], w1 = w1p[mq], w2 = w2p[mq];
#pragma unroll
      for (int j = 0; j < 4; ++j) {
        float4 v = vsrc[j * 32 + mq];
        acc0[j] += v.x * w0.x + v.y * w0.y + v.z * w0.z + v.w * w0.w;
        acc1[j] += v.x * w1.x + v.y * w1.y + v.z * w1.z + v.w * w1.w;
        acc2[j] += v.x * w2.x + v.y * w2.y + v.z * w2.z + v.w * w2.w;
      }
    }
    if (side) {
#pragma unroll
      for (int j = 0; j < 4; ++j) {
        ghbuf[0][j][kl] = acc0[j] + b0;
        ghbuf[1][j][kl] = acc1[j] + b1;
        ghbuf[2][j][kl] = acc2[j] + b2;
      }
    }
    __syncthreads();
    if (!side) {
#pragma unroll
      for (int j = 0; j < 4; ++j) {
        float rr = 1.0f / (1.0f + expf(-(acc0[j] + b0 + ghbuf[0][j][kl])));
        float zz = 1.0f / (1.0f + expf(-(acc1[j] + b1 + ghbuf[1][j][kl])));
        float nn = tanhf(acc2[j] + b2 + rr * ghbuf[2][j][kl]);
        float h = hbuf[j][kl];
        float hn = (1.0f - zz) * nn + zz * h;
        hbuf[j][kl] = hn;
        snap[((size_t)tb * FF + kl) * FF + j0 + j] = hn;
      }
    }
  }
}

// ------- batched GEMM + bias + relu (+ optional fused next-layer scores) ----
// out[tb][n][:] = relu(A[tb][n][:] @ Wsnap[tb] + bias); grid (ceil(N/128), 2b, Tz)
// Output: fp32 (outf) or bf16 (outb) — exactly one non-null.
__global__ __launch_bounds__(256) void gemm_kernel(
    const float* __restrict__ A, size_t a_tstride, size_t a_bstride,
    const float* __restrict__ Wsnap, const float* __restrict__ bias,
    float* __restrict__ outf, unsigned short* __restrict__ outb,
    size_t o_tstride, size_t o_bstride,
    const float* __restrict__ p1, const float* __restrict__ pinv1,
    unsigned long long* __restrict__ keys, int* __restrict__ hist, int N) {
  int nb = blockIdx.x, b = blockIdx.y, t = blockIdx.z;
  int tb = t * 2 + b;
  __shared__ float Ast[32][132];   // transposed: [kk][row]
  __shared__ float Bs[32][128];
  __shared__ float spart[128][17];
  __shared__ float p1s[128];
  int tid = threadIdx.x;
  int tc = tid & 15, tr = tid >> 4;
  if (p1 && tid < 128) p1s[tid] = p1[tid];
  float acc[8][8] = {};
  const float* Ab = A + (size_t)t * a_tstride + (size_t)b * a_bstride;
  const float* Wb = Wsnap + (size_t)tb * FF * FF;
  for (int kc = 0; kc < 4; ++kc) {
    int k0 = kc * 32;
    __syncthreads();
    for (int e = tid; e < 128 * 32; e += 256) {
      int r = e >> 5, kk = e & 31;
      int n = nb * 128 + r;
      Ast[kk][r] = (n < N) ? Ab[(size_t)n * FF + k0 + kk] : 0.f;
    }
    for (int e = tid; e < 32 * 128; e += 256) {
      int r = e >> 7, dd = e & 127;
      Bs[r][dd] = Wb[(k0 + r) * FF + dd];
    }
    __syncthreads();
#pragma unroll 4
    for (int kk = 0; kk < 32; ++kk) {
      const float4* arow = (const float4*)Ast[kk];
      float4 a0 = arow[tr * 2], a1 = arow[tr * 2 + 1];
      const float4* brow = (const float4*)Bs[kk];
      float4 b0 = brow[tc * 2], b1 = brow[tc * 2 + 1];
      float av[8] = {a0.x, a0.y, a0.z, a0.w, a1.x, a1.y, a1.z, a1.w};
      float bv[8] = {b0.x, b0.y, b0.z, b0.w, b1.x, b1.y, b1.z, b1.w};
#pragma unroll
      for (int i = 0; i < 8; ++i)
#pragma unroll
        for (int j = 0; j < 8; ++j) acc[i][j] += av[i] * bv[j];
    }
  }
  float bb[8];
#pragma unroll
  for (int j = 0; j < 8; ++j) bb[j] = bias[tc * 8 + j];
  size_t obase = (size_t)t * o_tstride + (size_t)b * o_bstride;
#pragma unroll
  for (int i = 0; i < 8; ++i) {
    int n = nb * 128 + tr * 8 + i;
    float v[8]; float part = 0.f;
#pragma unroll
    for (int j = 0; j < 8; ++j) {
      v[j] = fmaxf(acc[i][j] + bb[j], 0.f);
      if (p1) part += v[j] * p1s[tc * 8 + j];
    }
    if (n < N) {
      if (outb) {
        unsigned short* dst = outb + obase + (size_t)n * FF + tc * 8;
        uint4 pk;
        pk.x = (unsigned)f2bf(v[0]) | ((unsigned)f2bf(v[1]) << 16);
        pk.y = (unsigned)f2bf(v[2]) | ((unsigned)f2bf(v[3]) << 16);
        pk.z = (unsigned)f2bf(v[4]) | ((unsigned)f2bf(v[5]) << 16);
        pk.w = (unsigned)f2bf(v[6]) | ((unsigned)f2bf(v[7]) << 16);
        *(uint4*)dst = pk;
      } else {
        float4* dst = (float4*)(outf + obase + (size_t)n * FF + tc * 8);
        dst[0] = make_float4(v[0], v[1], v[2], v[3]);
        dst[1] = make_float4(v[4], v[5], v[6], v[7]);
      }
    }
    if (p1) spart[tr * 8 + i][tc] = part;
  }
  if (p1) {
    __syncthreads();
    if (tid < 128) {
      int n = nb * 128 + tid;
      if (n < N) {
        float s = 0.f;
#pragma unroll
        for (int q = 0; q < 16; ++q) s += spart[tid][q];
        s *= *pinv1;
        unsigned u = __float_as_uint(s);
        u = (u & 0x80000000u) ? ~u : (u | 0x80000000u);
        keys[(size_t)tb * N + n] = ((unsigned long long)u << 32) | (unsigned)(~n);
        atomicAdd(&hist[tb * BINS + (u >> 19)], 1);
      }
    }
  }
}

// ---------------- host ----------------
extern "C" void kernel_launch(void* const* d_in, const int* in_sizes, int n_in,
                              void* d_out, int out_size, void* d_ws, size_t ws_size,
                              hipStream_t stream) {
  const float* x   = (const float*)d_in[0];
  const void*  ei  = d_in[1];
  const float* ew  = (const float*)d_in[2];
  const float* W0  = (const float*)d_in[3];
  const float* p   = (const float*)d_in[4];
  const float* wih = (const float*)d_in[5];
  const float* whh = (const float*)d_in[6];
  const float* bih = (const float*)d_in[7];
  const float* bhh = (const float*)d_in[8];
  const float* bias= (const float*)d_in[9];

  const int E  = in_sizes[2];
  const int N  = in_sizes[0] / (BB * TT * FF);
  const int EN = E + N;
  const size_t NF = (size_t)N * FF;

  char* w = (char*)d_ws;
  auto alloc = [&](size_t bytes) -> char* {
    char* r = w; w += (bytes + 255) & ~(size_t)255; return r;
  };
  // ---- zero region (single memset) ----
  char* zbeg = w;
  float* deg      = (float*)alloc((size_t)N * 4);
  int*   counts   = (int*)  alloc((size_t)N * 4);
  int*   cursors  = (int*)  alloc((size_t)N * 4);
  int*   flag     = (int*)  alloc(4);
  int*   hist     = (int*)  alloc((size_t)2 * TT * BB * BINS * 4);
  char* zend = w;
  // ---- rest ----
  int*   offsets  = (int*)  alloc((size_t)(N + 1) * 4);
  float* dinv     = (float*)alloc((size_t)N * 4);
  float* pinv     = (float*)alloc(2 * 4);
  int2*  ep       = (int2*) alloc((size_t)EN * 8);
  unsigned long long* keys0 = (unsigned long long*)alloc((size_t)TT * BB * N * 8);
  unsigned long long* keys1 = (unsigned long long*)alloc((size_t)TT * BB * N * 8);
  int*   idx0     = (int*)  alloc((size_t)TT * BB * 128 * 4);
  float* gate0    = (float*)alloc((size_t)TT * BB * 128 * 4);
  int*   idx1     = (int*)  alloc((size_t)TT * BB * 128 * 4);
  float* gate1    = (float*)alloc((size_t)TT * BB * 128 * 4);
  float* W0snap   = (float*)alloc((size_t)TT * BB * FF * FF * 4);
  float* W1snap   = (float*)alloc((size_t)TT * BB * FF * FF * 4);
  float* xp       = (float*)alloc((size_t)TT * BB * NF * 4);  // A·x[t], fp32
  unsigned short* act0 = (unsigned short*)alloc((size_t)TT * BB * NF * 2); // bf16
  float* xq       = (float*)alloc((size_t)BB * NF * 4);       // A·act0[7], fp32
  int* hist0 = hist;
  int* hist1 = hist + (size_t)TT * BB * BINS;

  hipMemsetAsync(zbeg, 0, (size_t)(zend - zbeg), stream);

  // graph preprocessing (CSR by destination + symmetric norm)
  prep_kernel<<<3, 256, 0, stream>>>((const int*)ei, E, flag, p, pinv);
  hist_kernel<<<(EN + 255) / 256, 256, 0, stream>>>(ei, flag, E, N, ew, deg, counts);
  scan_kernel<<<1, 1024, 0, stream>>>(counts, deg, offsets, dinv, N, EN);
  scatter_kernel<<<(EN + 255) / 256, 256, 0, stream>>>(ei, flag, E, N, ew, dinv,
                                                       offsets, cursors, ep);

  // xp[t][b] = A · x[b][t] for all t, with fused layer-0 scores
  prop_kernel<0><<<dim3((N + 3) / 4, TT), 256, 0, stream>>>(
      x, NF, (size_t)TT * NF, xp, (size_t)BB * NF, NF,
      ep, offsets, p, pinv, keys0, hist0, N);

  selectsort_kernel<<<dim3(BB, TT), 1024, 0, stream>>>(
      keys0, hist0, N, idx0, gate0);

  // whole layer-0 W chain (8 GRU steps)
  wchain_kernel<0><<<dim3(BB, 32), 256, 0, stream>>>(
      x, NF, (size_t)TT * NF, idx0, gate0, W0,
      wih, whh, bih, bhh, W0snap);

  // act0[t][b] = relu(xp @ W0_t + bias0) -> bf16, fused layer-1 scores (fp32)
  gemm_kernel<<<dim3((N + 127) / 128, BB, TT), 256, 0, stream>>>(
      xp, (size_t)BB * NF, NF, W0snap, bias,
      nullptr, act0, (size_t)BB * NF, NF,
      p + FF, pinv + 1, keys1, hist1, N);

  selectsort_kernel<<<dim3(BB, TT), 1024, 0, stream>>>(
      keys1, hist1, N, idx1, gate1);

  // layer-1 W chain (bf16 pooled gathers)
  wchain_kernel<1><<<dim3(BB, 32), 256, 0, stream>>>(
      act0, (size_t)BB * NF, NF, idx1, gate1, W0 + FF * FF,
      wih + (size_t)GG * FF, whh + (size_t)GG * FF,
      bih + GG, bhh + GG, W1snap);

  // xq[b] = A · act0[7][b]  (bf16 gather, fp32 accumulate)
  prop_kernel<1><<<dim3((N + 3) / 4, 1), 256, 0, stream>>>(
      act0 + (size_t)(TT - 1) * BB * NF, 0, NF, xq, 0, NF,
      ep, offsets, nullptr, nullptr, nullptr, nullptr, N);

  // d_out = relu(xq @ W1_7 + bias1), fp32
  gemm_kernel<<<dim3((N + 127) / 128, BB, 1), 256, 0, stream>>>(
      xq, 0, NF, W1snap + (size_t)(TT - 1) * BB * FF * FF, bias + FF,
      (float*)d_out, nullptr, 0, NF,
      nullptr, nullptr, nullptr, nullptr, N);
}